// Round 8
// baseline (423.335 us; speedup 1.0000x reference)
//
#include <hip/hip_runtime.h>
#include <hip/hip_bf16.h>

// ---------------------------------------------------------------------------
// RRN forward, MI355X.
//   k0: unified prep — frag-pack ALL f16 hi/lo weights (Wf2 + 7 tail mats)
//       + Wf1 64x64 tile transpose -> WT1.
//   k1: A32/B32 projections (fp32) via WT1 (coalesced weight reads).
//   k2: pairwise MLP, CHUNKED producer/consumer: h staged 8-i at a time into
//       128KB LDS double buffer; inner 8-i loop is barrier-free pure MFMA.
//       (round-7 math, bit-identical: fp32 h single-rounded to f16, W hi/lo)
//   k4: fused MFMA tail (round-5 verified).
// ---------------------------------------------------------------------------

#define NN   512
#define HH   128
#define F1D  256
#define F2D  256
#define OUTD 64
#define ICHUNK 64

typedef _Float16 half_t;
typedef _Float16 half8 __attribute__((ext_vector_type(8)));
typedef float float4_t __attribute__((ext_vector_type(4)));
typedef float float8_t __attribute__((ext_vector_type(8)));

__device__ __forceinline__ float sigmoidf_(float x) {
    return 1.0f / (1.0f + __expf(-x));
}

#define HL_INV 2.44140625e-4f

// ---- workspace layout (bytes) ----
// A32 0 (512K) | B32 524288 (512K) | W2H 1048576 (128K) | W2L 1179648 (128K)
// S 1310720 (512K) | tail 1835008..3342336 (1.507M) | WT1 3342336 (256K)
#define WS_TAIL_B 1835008
#define WS_WT1_B  3342336
// f16-element offsets within tail region (hi base; lo = hi + cnt):
#define T3H 0
#define G1H 65536
#define G2H 196608
#define G3H 327680
#define CATH 393216
#define O1H 655360
#define O2H 720896

// ---------------- k0: unified weight prep ----------------
__constant__ int p_cum[8]   = {16, 24, 40, 56, 64, 96, 112, 116};
__constant__ int p_K[8]     = {256, 256, 256, 256, 256, 256, 128, 256};
__constant__ int p_hioff[8] = {0, T3H, G1H, G2H, G3H, CATH, O1H, O2H};
__constant__ int p_cnt[8]   = {65536, 32768, 65536, 65536, 32768, 131072, 32768, 16384};

__global__ __launch_bounds__(256)
void k0_prep(const float* __restrict__ Wf1,
             const float* __restrict__ Wf2,
             const float* __restrict__ Wf3,
             const float* __restrict__ Wg1, const float* __restrict__ Wg2,
             const float* __restrict__ Wg3,
             const float* __restrict__ W_ih, const float* __restrict__ W_hh,
             const float* __restrict__ Wo1, const float* __restrict__ Wo2,
             half_t* __restrict__ tail,
             half_t* __restrict__ W2H, half_t* __restrict__ W2L,
             float* __restrict__ WT1) {
    __shared__ float slab[4096];
    __shared__ float tile[64][65];
    const int t = threadIdx.x;
    const int bid = blockIdx.x;

    if (bid < 116) {
        int m = 0;
        while (m < 7 && bid >= p_cum[m]) ++m;
        const int pl = bid - (m ? p_cum[m - 1] : 0);
        const int K = p_K[m];
        const int kshift = (K == 256) ? 8 : 7;
        const int n0 = pl * 16;

        const float* src;
        switch (m) {
            case 0: src = Wf2; break;
            case 1: src = Wf3; break;
            case 2: src = Wg1; break;
            case 3: src = Wg2; break;
            case 4: src = Wg3; break;
            case 6: src = Wo1; break;
            default: src = Wo2; break;  // m==7 ; m==5 handled below
        }
        for (int q = t; q < (16 * K) / 4; q += 256) {
            const int flat = q * 4;
            const int r = flat >> kshift;
            const int k = flat & (K - 1);
            float4_t v;
            if (m == 5) {
                v = (k < 128) ? *(const float4_t*)(W_ih + (n0 + r) * 128 + k)
                              : *(const float4_t*)(W_hh + (n0 + r) * 128 + (k - 128));
            } else {
                v = *(const float4_t*)(src + (size_t)(n0 + r) * K + k);
            }
            *(float4_t*)&slab[flat] = v;
        }
        __syncthreads();

        half_t *hi, *lo;
        if (m == 0) { hi = W2H; lo = W2L; }
        else        { hi = tail + p_hioff[m]; lo = hi + p_cnt[m]; }
        const int base = pl * (K << 4);
        for (int f0 = t * 8; f0 < 16 * K; f0 += 2048) {
            const int ks = f0 >> 9;
            const int g4 = (f0 >> 7) & 3;
            const int l15 = (f0 >> 3) & 15;
            const int k0 = ks * 32 + g4 * 8;
            float8_t v = *(const float8_t*)&slab[l15 * K + k0];
            half8 hv, lv;
#pragma unroll
            for (int e = 0; e < 8; ++e) {
                half_t h = (half_t)v[e];
                hv[e] = h;
                lv[e] = (half_t)((v[e] - (float)h) * 4096.0f);
            }
            *(half8*)(hi + base + f0) = hv;
            *(half8*)(lo + base + f0) = lv;
        }
    } else {
        // Wf1 [256][256] transpose -> WT1[k][n]
        const int local = bid - 116;
        const int tr = local >> 2, tc = local & 3;
#pragma unroll
        for (int q = 0; q < 16; ++q) {
            const int idx = q * 256 + t;
            const int ly = idx >> 6, lx = idx & 63;
            tile[ly][lx] = Wf1[(tr * 64 + ly) * 256 + tc * 64 + lx];
        }
        __syncthreads();
#pragma unroll
        for (int q = 0; q < 16; ++q) {
            const int idx = q * 256 + t;
            const int ly = idx >> 6, lx = idx & 63;
            WT1[(tc * 64 + ly) * 256 + tr * 64 + lx] = tile[lx][ly];
        }
    }
}

// ---------------- k1: projections (fp32 out), coalesced via WT1 ----------------
__global__ __launch_bounds__(256)
void k1_proj(const float* __restrict__ hidden,
             const float* __restrict__ WT1,
             const float* __restrict__ bf1,
             float* __restrict__ A32,
             float* __restrict__ B32) {
    __shared__ float hid[4][HH];
    const int t = threadIdx.x;
    const int i0 = blockIdx.x * 4;
    for (int q = t; q < 4 * HH; q += 256)
        hid[q >> 7][q & 127] = hidden[(i0 + (q >> 7)) * HH + (q & 127)];
    __syncthreads();

    float accA[4], accB[4];
    const float b = bf1[t];
#pragma unroll
    for (int r = 0; r < 4; ++r) { accA[r] = b; accB[r] = 0.0f; }

    const float* wcol = WT1 + t;
#pragma unroll 4
    for (int kk = 0; kk < HH; ++kk) {
        const float va = wcol[kk * 256];
        const float vb = wcol[(kk + 128) * 256];
#pragma unroll
        for (int r = 0; r < 4; ++r) {
            const float h = hid[r][kk];
            accA[r] = fmaf(h, va, accA[r]);
            accB[r] = fmaf(h, vb, accB[r]);
        }
    }
#pragma unroll
    for (int r = 0; r < 4; ++r) {
        A32[(i0 + r) * F1D + t] = accA[r];
        B32[(i0 + r) * F1D + t] = accB[r];
    }
}

// ---------------- k2: pairwise MLP, chunked barrier-free inner loop ----------------
// grid (8 i-macrochunks, 32 j-tiles) x 512 threads (8 waves), 1 block/CU.
// hbuf[2][8 i][8 ks][512]: 128 KB double-buffered h staging.
// Per 8-i chunk: ONE barrier. Wave w produces k-slice ks=w for the NEXT
// chunk (loads issued before this chunk's MFMAs -> latency hidden), and
// consumes all 8 ks for its n-range [w*32, +32).
__global__ __launch_bounds__(512, 2)
void k2_pairwise(const float* __restrict__ A32,
                 const float* __restrict__ B32,
                 const half_t* __restrict__ W2H,
                 const half_t* __restrict__ W2L,
                 const float* __restrict__ bf2,
                 float* __restrict__ S) {
    __shared__ half_t hbuf[2][8][8][512];   // 128 KB

    const int tid = threadIdx.x;
    const int lane = tid & 63;
    const int w = tid >> 6;           // wave 0..7
    const int l15 = lane & 15;
    const int g4 = lane >> 4;         // 0..3
    const int j0 = blockIdx.y * 16;
    const int i0 = blockIdx.x * ICHUNK;
    const int lane8 = lane * 8;

    // W fragments, frag-packed (coalesced): half8 idx = (w*2+nt)*512 + ks*64 + lane
    const half8* WH8 = (const half8*)W2H;
    const half8* WL8 = (const half8*)W2L;
    half8 Wh[2][8], Wl[2][8];
#pragma unroll
    for (int nt = 0; nt < 2; ++nt)
#pragma unroll
        for (int ks = 0; ks < 8; ++ks) {
            const int idx = (w * 2 + nt) * 512 + ks * 64 + lane;
            Wh[nt][ks] = WH8[idx];
            Wl[nt][ks] = WL8[idx];
        }
#pragma unroll
    for (int nt = 0; nt < 2; ++nt)
#pragma unroll
        for (int ks = 0; ks < 8; ++ks) {
            asm volatile("" : "+v"(Wh[nt][ks]));
            asm volatile("" : "+v"(Wl[nt][ks]));
        }

    // producer's B slice: B[j=l15][k = w*32 + g4*8 .. +8]
    float4_t Bw0 = *(const float4_t*)(B32 + (size_t)(j0 + l15) * F1D + w * 32 + g4 * 8);
    float4_t Bw1 = *(const float4_t*)(B32 + (size_t)(j0 + l15) * F1D + w * 32 + g4 * 8 + 4);

    float b2v[2];
#pragma unroll
    for (int nt = 0; nt < 2; ++nt) b2v[nt] = bf2[w * 32 + nt * 16 + l15];

    float4_t acc[2];
#pragma unroll
    for (int nt = 0; nt < 2; ++nt)
#pragma unroll
        for (int r = 0; r < 4; ++r) acc[nt][r] = 0.0f;

    // ---- prologue: stage chunk 0 into buf 0 ----
#pragma unroll
    for (int q = 0; q < 8; ++q) {
        const float* Ap = A32 + (size_t)(i0 + q) * F1D + w * 32 + g4 * 8;
        float4_t a0 = *(const float4_t*)Ap;
        float4_t a1 = *(const float4_t*)(Ap + 4);
        half8 hf;
#pragma unroll
        for (int e = 0; e < 4; ++e) {
            hf[e]     = (half_t)fmaxf(a0[e] + Bw0[e], 0.0f);
            hf[4 + e] = (half_t)fmaxf(a1[e] + Bw1[e], 0.0f);
        }
        *(half8*)&hbuf[0][q][w][lane8] = hf;
    }
    __syncthreads();

    // ---- 8 chunks of 8 i ----
    for (int c = 0; c < 8; ++c) {
        const int cur = c & 1;
        const int nxt = cur ^ 1;
        const int inext = i0 + (c + 1) * 8;

        // issue first half of next chunk's A loads (covered by MFMA i 0..3)
        float4_t av[4][2];
        if (c < 7) {
#pragma unroll
            for (int q = 0; q < 4; ++q) {
                const float* Ap = A32 + (size_t)(inext + q) * F1D + w * 32 + g4 * 8;
                av[q][0] = *(const float4_t*)Ap;
                av[q][1] = *(const float4_t*)(Ap + 4);
            }
        }

        // MFMA i = 0..3 of current chunk
#pragma unroll
        for (int q = 0; q < 4; ++q) {
            float4_t C[2], Cl[2];
#pragma unroll
            for (int nt = 0; nt < 2; ++nt)
#pragma unroll
                for (int r = 0; r < 4; ++r) { C[nt][r] = 0.0f; Cl[nt][r] = 0.0f; }
#pragma unroll
            for (int ks = 0; ks < 8; ++ks) {
                half8 hf = *(const half8*)&hbuf[cur][q][ks][lane8];
                C[0]  = __builtin_amdgcn_mfma_f32_16x16x32_f16(hf, Wh[0][ks], C[0], 0, 0, 0);
                C[1]  = __builtin_amdgcn_mfma_f32_16x16x32_f16(hf, Wh[1][ks], C[1], 0, 0, 0);
                Cl[0] = __builtin_amdgcn_mfma_f32_16x16x32_f16(hf, Wl[0][ks], Cl[0], 0, 0, 0);
                Cl[1] = __builtin_amdgcn_mfma_f32_16x16x32_f16(hf, Wl[1][ks], Cl[1], 0, 0, 0);
            }
#pragma unroll
            for (int nt = 0; nt < 2; ++nt)
#pragma unroll
                for (int r = 0; r < 4; ++r) {
                    float v = fmaf(Cl[nt][r], HL_INV, C[nt][r]) + b2v[nt];
                    acc[nt][r] += fmaxf(v, 0.0f);
                }
        }

        // write h (next chunk, i 0..3); issue second half of loads
        if (c < 7) {
#pragma unroll
            for (int q = 0; q < 4; ++q) {
                half8 hf;
#pragma unroll
                for (int e = 0; e < 4; ++e) {
                    hf[e]     = (half_t)fmaxf(av[q][0][e] + Bw0[e], 0.0f);
                    hf[4 + e] = (half_t)fmaxf(av[q][1][e] + Bw1[e], 0.0f);
                }
                *(half8*)&hbuf[nxt][q][w][lane8] = hf;
            }
#pragma unroll
            for (int q = 0; q < 4; ++q) {
                const float* Ap = A32 + (size_t)(inext + 4 + q) * F1D + w * 32 + g4 * 8;
                av[q][0] = *(const float4_t*)Ap;
                av[q][1] = *(const float4_t*)(Ap + 4);
            }
        }

        // MFMA i = 4..7 of current chunk
#pragma unroll
        for (int q = 4; q < 8; ++q) {
            float4_t C[2], Cl[2];
#pragma unroll
            for (int nt = 0; nt < 2; ++nt)
#pragma unroll
                for (int r = 0; r < 4; ++r) { C[nt][r] = 0.0f; Cl[nt][r] = 0.0f; }
#pragma unroll
            for (int ks = 0; ks < 8; ++ks) {
                half8 hf = *(const half8*)&hbuf[cur][q][ks][lane8];
                C[0]  = __builtin_amdgcn_mfma_f32_16x16x32_f16(hf, Wh[0][ks], C[0], 0, 0, 0);
                C[1]  = __builtin_amdgcn_mfma_f32_16x16x32_f16(hf, Wh[1][ks], C[1], 0, 0, 0);
                Cl[0] = __builtin_amdgcn_mfma_f32_16x16x32_f16(hf, Wl[0][ks], Cl[0], 0, 0, 0);
                Cl[1] = __builtin_amdgcn_mfma_f32_16x16x32_f16(hf, Wl[1][ks], Cl[1], 0, 0, 0);
            }
#pragma unroll
            for (int nt = 0; nt < 2; ++nt)
#pragma unroll
                for (int r = 0; r < 4; ++r) {
                    float v = fmaf(Cl[nt][r], HL_INV, C[nt][r]) + b2v[nt];
                    acc[nt][r] += fmaxf(v, 0.0f);
                }
        }

        // write h (next chunk, i 4..7)
        if (c < 7) {
#pragma unroll
            for (int q = 0; q < 4; ++q) {
                half8 hf;
#pragma unroll
                for (int e = 0; e < 4; ++e) {
                    hf[e]     = (half_t)fmaxf(av[q][0][e] + Bw0[e], 0.0f);
                    hf[4 + e] = (half_t)fmaxf(av[q][1][e] + Bw1[e], 0.0f);
                }
                *(half8*)&hbuf[nxt][4 + q][w][lane8] = hf;
            }
        }
        __syncthreads();
    }

    // C layout: col = l15 (n), row = g4*4 + r (jj)
#pragma unroll
    for (int nt = 0; nt < 2; ++nt)
#pragma unroll
        for (int r = 0; r < 4; ++r)
            atomicAdd(&S[(size_t)(j0 + g4 * 4 + r) * F2D + w * 32 + nt * 16 + l15], acc[nt][r]);
}

// ---------------- k4: fused MFMA tail (round-5 verified) ----------------
#define AST 260   // LDS activation row stride (floats)

template<int NT, int NKS>
__device__ __forceinline__ void frag_gemm(const float* __restrict__ aPtr,
                                          const half_t* __restrict__ WhF,
                                          const half_t* __restrict__ WlF,
                                          const int* pB, int lane8,
                                          float4_t* Chi, float4_t* Clo) {
#pragma unroll
    for (int ks = 0; ks < NKS; ++ks) {
        float4_t a0 = *(const float4_t*)(aPtr + ks * 32);
        float4_t a1 = *(const float4_t*)(aPtr + ks * 32 + 4);
        half8 ah, al;
#pragma unroll
        for (int e = 0; e < 4; ++e) {
            half_t h0 = (half_t)a0[e];
            ah[e] = h0; al[e] = (half_t)((a0[e] - (float)h0) * 4096.0f);
            half_t h1 = (half_t)a1[e];
            ah[4+e] = h1; al[4+e] = (half_t)((a1[e] - (float)h1) * 4096.0f);
        }
#pragma unroll
        for (int nt = 0; nt < NT; ++nt) {
            half8 wh = *(const half8*)(WhF + pB[nt] + ks * 512 + lane8);
            half8 wl = *(const half8*)(WlF + pB[nt] + ks * 512 + lane8);
            Chi[nt] = __builtin_amdgcn_mfma_f32_16x16x32_f16(ah, wh, Chi[nt], 0, 0, 0);
            Clo[nt] = __builtin_amdgcn_mfma_f32_16x16x32_f16(ah, wl, Clo[nt], 0, 0, 0);
            Clo[nt] = __builtin_amdgcn_mfma_f32_16x16x32_f16(al, wh, Clo[nt], 0, 0, 0);
        }
    }
}

__global__ __launch_bounds__(512)
void k4_tail(const float* __restrict__ S,
             const float* __restrict__ x,
             const float* __restrict__ h0,
             const float* __restrict__ c0,
             const half_t* __restrict__ tail,
             const float* __restrict__ bf3,
             const float* __restrict__ bg1, const float* __restrict__ bg2,
             const float* __restrict__ bg3,
             const float* __restrict__ b_ih, const float* __restrict__ b_hh,
             const float* __restrict__ bo1, const float* __restrict__ bo2,
             float* __restrict__ out,
             float* __restrict__ hid_out,
             float* __restrict__ h_out,
             float* __restrict__ c_out) {
    __shared__ float bufA[16 * AST];
    __shared__ float bufB[16 * AST];
    __shared__ float bufC[16 * AST];
    const int tid = threadIdx.x;
    const int lane = tid & 63;
    const int w = tid >> 6;
    const int l15 = lane & 15;
    const int g4 = lane >> 4;
    const int r0 = blockIdx.x * 16;
    const int lane8 = lane * 8;

    for (int q = tid; q < 16 * 256; q += 512)
        bufC[(q >> 8) * AST + (q & 255)] = S[(size_t)(r0 + (q >> 8)) * 256 + (q & 255)];
    for (int q = tid; q < 16 * 128; q += 512)
        bufA[(q >> 7) * AST + (q & 127)] = x[(r0 + (q >> 7)) * 128 + (q & 127)];
    __syncthreads();

    const float* aFrag;
    int pB[4];
    float4_t Chi[4], Clo[4];

    // ---- SM ----
    {
        const int n = w * 16 + l15;
        pB[0] = w * 4096;
        Chi[0] = float4_t{0,0,0,0}; Clo[0] = float4_t{0,0,0,0};
        aFrag = bufC + l15 * AST + g4 * 8;
        frag_gemm<1, 8>(aFrag, tail + T3H, tail + T3H + 32768, pB, lane8, Chi, Clo);
        const float b = 512.0f * bf3[n];
#pragma unroll
        for (int r = 0; r < 4; ++r)
            bufA[(g4 * 4 + r) * AST + 128 + n] = Chi[0][r] + Clo[0][r] * HL_INV + b;
    }
    __syncthreads();

    // ---- g1 ----
    {
        pB[0] = (w * 2) * 4096; pB[1] = (w * 2 + 1) * 4096;
        Chi[0] = float4_t{0,0,0,0}; Clo[0] = float4_t{0,0,0,0};
        Chi[1] = float4_t{0,0,0,0}; Clo[1] = float4_t{0,0,0,0};
        aFrag = bufA + l15 * AST + g4 * 8;
        frag_gemm<2, 8>(aFrag, tail + G1H, tail + G1H + 65536, pB, lane8, Chi, Clo);
#pragma unroll
        for (int nt = 0; nt < 2; ++nt) {
            const int n = w * 32 + nt * 16 + l15;
            const float b = bg1[n];
#pragma unroll
            for (int r = 0; r < 4; ++r)
                bufB[(g4 * 4 + r) * AST + n] = fmaxf(Chi[nt][r] + Clo[nt][r] * HL_INV + b, 0.0f);
        }
    }
    __syncthreads();

    // ---- g2 (+ stage h0) ----
    {
        pB[0] = (w * 2) * 4096; pB[1] = (w * 2 + 1) * 4096;
        Chi[0] = float4_t{0,0,0,0}; Clo[0] = float4_t{0,0,0,0};
        Chi[1] = float4_t{0,0,0,0}; Clo[1] = float4_t{0,0,0,0};
        aFrag = bufB + l15 * AST + g4 * 8;
        frag_gemm<2, 8>(aFrag, tail + G2H, tail + G2H + 65536, pB, lane8, Chi, Clo);
#pragma unroll
        for (int nt = 0; nt < 2; ++nt) {
            const int n = w * 32 + nt * 16 + l15;
            const float b = bg2[n];
#pragma unroll
            for (int r = 0; r < 4; ++r)
                bufC[(g4 * 4 + r) * AST + n] = fmaxf(Chi[nt][r] + Clo[nt][r] * HL_INV + b, 0.0f);
        }
        for (int q = tid; q < 16 * 128; q += 512)
            bufA[(q >> 7) * AST + 128 + (q & 127)] = h0[(r0 + (q >> 7)) * 128 + (q & 127)];
    }
    __syncthreads();

    // ---- g3 ----
    {
        const int n = w * 16 + l15;
        pB[0] = w * 4096;
        Chi[0] = float4_t{0,0,0,0}; Clo[0] = float4_t{0,0,0,0};
        aFrag = bufC + l15 * AST + g4 * 8;
        frag_gemm<1, 8>(aFrag, tail + G3H, tail + G3H + 32768, pB, lane8, Chi, Clo);
        const float b = bg3[n];
#pragma unroll
        for (int r = 0; r < 4; ++r)
            bufA[(g4 * 4 + r) * AST + n] = Chi[0][r] + Clo[0][r] * HL_INV + b;
    }
    __syncthreads();

    // ---- gates + LSTM in-register ----
    {
#pragma unroll
        for (int nt = 0; nt < 4; ++nt) {
            pB[nt] = (w + nt * 8) * 4096;
            Chi[nt] = float4_t{0,0,0,0}; Clo[nt] = float4_t{0,0,0,0};
        }
        aFrag = bufA + l15 * AST + g4 * 8;
        frag_gemm<4, 8>(aFrag, tail + CATH, tail + CATH + 131072, pB, lane8, Chi, Clo);

        const int nh = w * 16 + l15;
        float bi = b_ih[nh]       + b_hh[nh];
        float bf = b_ih[128 + nh] + b_hh[128 + nh];
        float bg = b_ih[256 + nh] + b_hh[256 + nh];
        float bo = b_ih[384 + nh] + b_hh[384 + nh];
#pragma unroll
        for (int r = 0; r < 4; ++r) {
            const int row = r0 + g4 * 4 + r;
            float gi = sigmoidf_(Chi[0][r] + Clo[0][r] * HL_INV + bi);
            float gf = sigmoidf_(Chi[1][r] + Clo[1][r] * HL_INV + bf);
            float gg = tanhf(    Chi[2][r] + Clo[2][r] * HL_INV + bg);
            float go = sigmoidf_(Chi[3][r] + Clo[3][r] * HL_INV + bo);
            float c = gf * c0[row * 128 + nh] + gi * gg;
            float h = go * tanhf(c);
            bufC[(g4 * 4 + r) * AST + nh] = h;
            hid_out[row * 128 + nh] = h;
            h_out[row * 128 + nh]   = h;
            c_out[row * 128 + nh]   = c;
        }
    }
    __syncthreads();

    // ---- o1 ----
    {
        pB[0] = (w * 2) * 2048; pB[1] = (w * 2 + 1) * 2048;
        Chi[0] = float4_t{0,0,0,0}; Clo[0] = float4_t{0,0,0,0};
        Chi[1] = float4_t{0,0,0,0}; Clo[1] = float4_t{0,0,0,0};
        aFrag = bufC + l15 * AST + g4 * 8;
        frag_gemm<2, 4>(aFrag, tail + O1H, tail + O1H + 32768, pB, lane8, Chi, Clo);
#pragma unroll
        for (int nt = 0; nt < 2; ++nt) {
            const int n = w * 32 + nt * 16 + l15;
            const float b = bo1[n];
#pragma unroll
            for (int r = 0; r < 4; ++r)
                bufB[(g4 * 4 + r) * AST + n] = fmaxf(Chi[nt][r] + Clo[nt][r] * HL_INV + b, 0.0f);
        }
    }
    __syncthreads();

    // ---- o2 ----
    if (w < 4) {
        const int n = w * 16 + l15;
        pB[0] = w * 4096;
        Chi[0] = float4_t{0,0,0,0}; Clo[0] = float4_t{0,0,0,0};
        aFrag = bufB + l15 * AST + g4 * 8;
        frag_gemm<1, 8>(aFrag, tail + O2H, tail + O2H + 16384, pB, lane8, Chi, Clo);
        const float b = bo2[n];
#pragma unroll
        for (int r = 0; r < 4; ++r)
            out[(r0 + g4 * 4 + r) * OUTD + n] = Chi[0][r] + Clo[0][r] * HL_INV + b;
    }
}

// ---------------------------------------------------------------------------
extern "C" void kernel_launch(void* const* d_in, const int* in_sizes, int n_in,
                              void* d_out, int out_size, void* d_ws, size_t ws_size,
                              hipStream_t stream) {
    const float* x      = (const float*)d_in[0];
    const float* hidden = (const float*)d_in[1];
    const float* h0     = (const float*)d_in[2];
    const float* c0     = (const float*)d_in[3];
    const float* Wf1    = (const float*)d_in[4];
    const float* bf1    = (const float*)d_in[5];
    const float* Wf2    = (const float*)d_in[6];
    const float* bf2    = (const float*)d_in[7];
    const float* Wf3    = (const float*)d_in[8];
    const float* bf3    = (const float*)d_in[9];
    const float* Wg1    = (const float*)d_in[10];
    const float* bg1    = (const float*)d_in[11];
    const float* Wg2    = (const float*)d_in[12];
    const float* bg2    = (const float*)d_in[13];
    const float* Wg3    = (const float*)d_in[14];
    const float* bg3    = (const float*)d_in[15];
    const float* W_ih   = (const float*)d_in[16];
    const float* W_hh   = (const float*)d_in[17];
    const float* b_ih   = (const float*)d_in[18];
    const float* b_hh   = (const float*)d_in[19];
    const float* Wo1    = (const float*)d_in[20];
    const float* bo1    = (const float*)d_in[21];
    const float* Wo2    = (const float*)d_in[22];
    const float* bo2    = (const float*)d_in[23];

    char* wsb = (char*)d_ws;
    float*  A32  = (float*)(wsb + 0);
    float*  B32  = (float*)(wsb + 524288);
    half_t* W2H  = (half_t*)(wsb + 1048576);
    half_t* W2L  = (half_t*)(wsb + 1179648);
    float*  S    = (float*)(wsb + 1310720);
    half_t* tail = (half_t*)(wsb + WS_TAIL_B);
    float*  WT1  = (float*)(wsb + WS_WT1_B);

    float* outp  = (float*)d_out;              // [512,64]
    float* hid1  = (float*)d_out + 32768;      // hidden_new [512,128]
    float* hid2  = (float*)d_out + 98304;      // hidden_new[None]
    float* cout  = (float*)d_out + 163840;     // c_new[None]

    hipMemsetAsync(S, 0, (size_t)NN * F2D * sizeof(float), stream);

    k0_prep<<<dim3(132), dim3(256), 0, stream>>>(Wf1, Wf2, Wf3, Wg1, Wg2, Wg3,
                                                 W_ih, W_hh, Wo1, Wo2,
                                                 tail, W2H, W2L, WT1);

    k1_proj<<<dim3(128), dim3(256), 0, stream>>>(hidden, WT1, bf1, A32, B32);

    k2_pairwise<<<dim3(8, 32), dim3(512), 0, stream>>>(A32, B32, W2H, W2L, bf2, S);

    k4_tail<<<dim3(32), dim3(512), 0, stream>>>(S, x, h0, c0, tail,
                                                bf3, bg1, bg2, bg3,
                                                b_ih, b_hh, bo1, bo2,
                                                outp, hid1, hid2, cout);
}

// Round 9
// 415.191 us; speedup vs baseline: 1.0196x; 1.0196x over previous
//
#include <hip/hip_runtime.h>
#include <hip/hip_bf16.h>

// ---------------------------------------------------------------------------
// RRN forward, MI355X.
//   k0: unified prep — frag-pack ALL f16 hi/lo weights (Wf2 + 7 tail mats)
//       + Wf1 64x64 tile transpose -> WT1.
//   k1: A32/B32 projections (fp32) via WT1 (coalesced weight reads).
//   k2: pairwise MLP, CHUNKED producer/consumer: h staged 8-i at a time into
//       128KB LDS double buffer; inner 8-i loop is barrier-free pure MFMA.
//       FIX vs round 8: __launch_bounds__(512,1) -> 256-VGPR cap. The (512,2)
//       bound capped at 128 VGPR and spilled the whole W set to scratch
//       (676MB HBM fetch/dispatch). LDS=128KB already forces 1 block/CU.
//   k4: fused MFMA tail (round-5 verified).
// ---------------------------------------------------------------------------

#define NN   512
#define HH   128
#define F1D  256
#define F2D  256
#define OUTD 64
#define ICHUNK 64

typedef _Float16 half_t;
typedef _Float16 half8 __attribute__((ext_vector_type(8)));
typedef float float4_t __attribute__((ext_vector_type(4)));
typedef float float8_t __attribute__((ext_vector_type(8)));

__device__ __forceinline__ float sigmoidf_(float x) {
    return 1.0f / (1.0f + __expf(-x));
}

#define HL_INV 2.44140625e-4f

// ---- workspace layout (bytes) ----
// A32 0 (512K) | B32 524288 (512K) | W2H 1048576 (128K) | W2L 1179648 (128K)
// S 1310720 (512K) | tail 1835008..3342336 (1.507M) | WT1 3342336 (256K)
#define WS_TAIL_B 1835008
#define WS_WT1_B  3342336
// f16-element offsets within tail region (hi base; lo = hi + cnt):
#define T3H 0
#define G1H 65536
#define G2H 196608
#define G3H 327680
#define CATH 393216
#define O1H 655360
#define O2H 720896

// ---------------- k0: unified weight prep ----------------
__constant__ int p_cum[8]   = {16, 24, 40, 56, 64, 96, 112, 116};
__constant__ int p_K[8]     = {256, 256, 256, 256, 256, 256, 128, 256};
__constant__ int p_hioff[8] = {0, T3H, G1H, G2H, G3H, CATH, O1H, O2H};
__constant__ int p_cnt[8]   = {65536, 32768, 65536, 65536, 32768, 131072, 32768, 16384};

__global__ __launch_bounds__(256)
void k0_prep(const float* __restrict__ Wf1,
             const float* __restrict__ Wf2,
             const float* __restrict__ Wf3,
             const float* __restrict__ Wg1, const float* __restrict__ Wg2,
             const float* __restrict__ Wg3,
             const float* __restrict__ W_ih, const float* __restrict__ W_hh,
             const float* __restrict__ Wo1, const float* __restrict__ Wo2,
             half_t* __restrict__ tail,
             half_t* __restrict__ W2H, half_t* __restrict__ W2L,
             float* __restrict__ WT1) {
    __shared__ float slab[4096];
    __shared__ float tile[64][65];
    const int t = threadIdx.x;
    const int bid = blockIdx.x;

    if (bid < 116) {
        int m = 0;
        while (m < 7 && bid >= p_cum[m]) ++m;
        const int pl = bid - (m ? p_cum[m - 1] : 0);
        const int K = p_K[m];
        const int kshift = (K == 256) ? 8 : 7;
        const int n0 = pl * 16;

        const float* src;
        switch (m) {
            case 0: src = Wf2; break;
            case 1: src = Wf3; break;
            case 2: src = Wg1; break;
            case 3: src = Wg2; break;
            case 4: src = Wg3; break;
            case 6: src = Wo1; break;
            default: src = Wo2; break;  // m==7 ; m==5 handled below
        }
        for (int q = t; q < (16 * K) / 4; q += 256) {
            const int flat = q * 4;
            const int r = flat >> kshift;
            const int k = flat & (K - 1);
            float4_t v;
            if (m == 5) {
                v = (k < 128) ? *(const float4_t*)(W_ih + (n0 + r) * 128 + k)
                              : *(const float4_t*)(W_hh + (n0 + r) * 128 + (k - 128));
            } else {
                v = *(const float4_t*)(src + (size_t)(n0 + r) * K + k);
            }
            *(float4_t*)&slab[flat] = v;
        }
        __syncthreads();

        half_t *hi, *lo;
        if (m == 0) { hi = W2H; lo = W2L; }
        else        { hi = tail + p_hioff[m]; lo = hi + p_cnt[m]; }
        const int base = pl * (K << 4);
        for (int f0 = t * 8; f0 < 16 * K; f0 += 2048) {
            const int ks = f0 >> 9;
            const int g4 = (f0 >> 7) & 3;
            const int l15 = (f0 >> 3) & 15;
            const int k0 = ks * 32 + g4 * 8;
            float8_t v = *(const float8_t*)&slab[l15 * K + k0];
            half8 hv, lv;
#pragma unroll
            for (int e = 0; e < 8; ++e) {
                half_t h = (half_t)v[e];
                hv[e] = h;
                lv[e] = (half_t)((v[e] - (float)h) * 4096.0f);
            }
            *(half8*)(hi + base + f0) = hv;
            *(half8*)(lo + base + f0) = lv;
        }
    } else {
        // Wf1 [256][256] transpose -> WT1[k][n]
        const int local = bid - 116;
        const int tr = local >> 2, tc = local & 3;
#pragma unroll
        for (int q = 0; q < 16; ++q) {
            const int idx = q * 256 + t;
            const int ly = idx >> 6, lx = idx & 63;
            tile[ly][lx] = Wf1[(tr * 64 + ly) * 256 + tc * 64 + lx];
        }
        __syncthreads();
#pragma unroll
        for (int q = 0; q < 16; ++q) {
            const int idx = q * 256 + t;
            const int ly = idx >> 6, lx = idx & 63;
            WT1[(tc * 64 + ly) * 256 + tr * 64 + lx] = tile[lx][ly];
        }
    }
}

// ---------------- k1: projections (fp32 out), coalesced via WT1 ----------------
__global__ __launch_bounds__(256)
void k1_proj(const float* __restrict__ hidden,
             const float* __restrict__ WT1,
             const float* __restrict__ bf1,
             float* __restrict__ A32,
             float* __restrict__ B32) {
    __shared__ float hid[4][HH];
    const int t = threadIdx.x;
    const int i0 = blockIdx.x * 4;
    for (int q = t; q < 4 * HH; q += 256)
        hid[q >> 7][q & 127] = hidden[(i0 + (q >> 7)) * HH + (q & 127)];
    __syncthreads();

    float accA[4], accB[4];
    const float b = bf1[t];
#pragma unroll
    for (int r = 0; r < 4; ++r) { accA[r] = b; accB[r] = 0.0f; }

    const float* wcol = WT1 + t;
#pragma unroll 4
    for (int kk = 0; kk < HH; ++kk) {
        const float va = wcol[kk * 256];
        const float vb = wcol[(kk + 128) * 256];
#pragma unroll
        for (int r = 0; r < 4; ++r) {
            const float h = hid[r][kk];
            accA[r] = fmaf(h, va, accA[r]);
            accB[r] = fmaf(h, vb, accB[r]);
        }
    }
#pragma unroll
    for (int r = 0; r < 4; ++r) {
        A32[(i0 + r) * F1D + t] = accA[r];
        B32[(i0 + r) * F1D + t] = accB[r];
    }
}

// ---------------- k2: pairwise MLP, chunked barrier-free inner loop ----------------
// grid (8 i-macrochunks, 32 j-tiles) x 512 threads (8 waves), 1 block/CU
// (128KB LDS forces this). __launch_bounds__(512,1) -> 256-VGPR budget so the
// pinned W fragments + chunk state fit WITHOUT scratch spill.
__global__ __launch_bounds__(512, 1)
void k2_pairwise(const float* __restrict__ A32,
                 const float* __restrict__ B32,
                 const half_t* __restrict__ W2H,
                 const half_t* __restrict__ W2L,
                 const float* __restrict__ bf2,
                 float* __restrict__ S) {
    __shared__ half_t hbuf[2][8][8][512];   // 128 KB

    const int tid = threadIdx.x;
    const int lane = tid & 63;
    const int w = tid >> 6;           // wave 0..7
    const int l15 = lane & 15;
    const int g4 = lane >> 4;         // 0..3
    const int j0 = blockIdx.y * 16;
    const int i0 = blockIdx.x * ICHUNK;
    const int lane8 = lane * 8;

    // W fragments, frag-packed (coalesced): half8 idx = (w*2+nt)*512 + ks*64 + lane
    const half8* WH8 = (const half8*)W2H;
    const half8* WL8 = (const half8*)W2L;
    half8 Wh[2][8], Wl[2][8];
#pragma unroll
    for (int nt = 0; nt < 2; ++nt)
#pragma unroll
        for (int ks = 0; ks < 8; ++ks) {
            const int idx = (w * 2 + nt) * 512 + ks * 64 + lane;
            Wh[nt][ks] = WH8[idx];
            Wl[nt][ks] = WL8[idx];
        }
#pragma unroll
    for (int nt = 0; nt < 2; ++nt)
#pragma unroll
        for (int ks = 0; ks < 8; ++ks) {
            asm volatile("" : "+v"(Wh[nt][ks]));
            asm volatile("" : "+v"(Wl[nt][ks]));
        }

    // producer's B slice: B[j=l15][k = w*32 + g4*8 .. +8]
    float4_t Bw0 = *(const float4_t*)(B32 + (size_t)(j0 + l15) * F1D + w * 32 + g4 * 8);
    float4_t Bw1 = *(const float4_t*)(B32 + (size_t)(j0 + l15) * F1D + w * 32 + g4 * 8 + 4);

    float b2v[2];
#pragma unroll
    for (int nt = 0; nt < 2; ++nt) b2v[nt] = bf2[w * 32 + nt * 16 + l15];

    float4_t acc[2];
#pragma unroll
    for (int nt = 0; nt < 2; ++nt)
#pragma unroll
        for (int r = 0; r < 4; ++r) acc[nt][r] = 0.0f;

    // ---- prologue: stage chunk 0 into buf 0 ----
#pragma unroll
    for (int q = 0; q < 8; ++q) {
        const float* Ap = A32 + (size_t)(i0 + q) * F1D + w * 32 + g4 * 8;
        float4_t a0 = *(const float4_t*)Ap;
        float4_t a1 = *(const float4_t*)(Ap + 4);
        half8 hf;
#pragma unroll
        for (int e = 0; e < 4; ++e) {
            hf[e]     = (half_t)fmaxf(a0[e] + Bw0[e], 0.0f);
            hf[4 + e] = (half_t)fmaxf(a1[e] + Bw1[e], 0.0f);
        }
        *(half8*)&hbuf[0][q][w][lane8] = hf;
    }
    __syncthreads();

    // ---- 8 chunks of 8 i ----
    for (int c = 0; c < 8; ++c) {
        const int cur = c & 1;
        const int nxt = cur ^ 1;
        const int inext = i0 + (c + 1) * 8;

        // issue first half of next chunk's A loads (covered by MFMA i 0..3)
        float4_t av[4][2];
        if (c < 7) {
#pragma unroll
            for (int q = 0; q < 4; ++q) {
                const float* Ap = A32 + (size_t)(inext + q) * F1D + w * 32 + g4 * 8;
                av[q][0] = *(const float4_t*)Ap;
                av[q][1] = *(const float4_t*)(Ap + 4);
            }
        }

        // MFMA i = 0..3 of current chunk
#pragma unroll
        for (int q = 0; q < 4; ++q) {
            float4_t C[2], Cl[2];
#pragma unroll
            for (int nt = 0; nt < 2; ++nt)
#pragma unroll
                for (int r = 0; r < 4; ++r) { C[nt][r] = 0.0f; Cl[nt][r] = 0.0f; }
#pragma unroll
            for (int ks = 0; ks < 8; ++ks) {
                half8 hf = *(const half8*)&hbuf[cur][q][ks][lane8];
                C[0]  = __builtin_amdgcn_mfma_f32_16x16x32_f16(hf, Wh[0][ks], C[0], 0, 0, 0);
                C[1]  = __builtin_amdgcn_mfma_f32_16x16x32_f16(hf, Wh[1][ks], C[1], 0, 0, 0);
                Cl[0] = __builtin_amdgcn_mfma_f32_16x16x32_f16(hf, Wl[0][ks], Cl[0], 0, 0, 0);
                Cl[1] = __builtin_amdgcn_mfma_f32_16x16x32_f16(hf, Wl[1][ks], Cl[1], 0, 0, 0);
            }
#pragma unroll
            for (int nt = 0; nt < 2; ++nt)
#pragma unroll
                for (int r = 0; r < 4; ++r) {
                    float v = fmaf(Cl[nt][r], HL_INV, C[nt][r]) + b2v[nt];
                    acc[nt][r] += fmaxf(v, 0.0f);
                }
        }

        // write h (next chunk, i 0..3); issue second half of loads
        if (c < 7) {
#pragma unroll
            for (int q = 0; q < 4; ++q) {
                half8 hf;
#pragma unroll
                for (int e = 0; e < 4; ++e) {
                    hf[e]     = (half_t)fmaxf(av[q][0][e] + Bw0[e], 0.0f);
                    hf[4 + e] = (half_t)fmaxf(av[q][1][e] + Bw1[e], 0.0f);
                }
                *(half8*)&hbuf[nxt][q][w][lane8] = hf;
            }
#pragma unroll
            for (int q = 0; q < 4; ++q) {
                const float* Ap = A32 + (size_t)(inext + 4 + q) * F1D + w * 32 + g4 * 8;
                av[q][0] = *(const float4_t*)Ap;
                av[q][1] = *(const float4_t*)(Ap + 4);
            }
        }

        // MFMA i = 4..7 of current chunk
#pragma unroll
        for (int q = 4; q < 8; ++q) {
            float4_t C[2], Cl[2];
#pragma unroll
            for (int nt = 0; nt < 2; ++nt)
#pragma unroll
                for (int r = 0; r < 4; ++r) { C[nt][r] = 0.0f; Cl[nt][r] = 0.0f; }
#pragma unroll
            for (int ks = 0; ks < 8; ++ks) {
                half8 hf = *(const half8*)&hbuf[cur][q][ks][lane8];
                C[0]  = __builtin_amdgcn_mfma_f32_16x16x32_f16(hf, Wh[0][ks], C[0], 0, 0, 0);
                C[1]  = __builtin_amdgcn_mfma_f32_16x16x32_f16(hf, Wh[1][ks], C[1], 0, 0, 0);
                Cl[0] = __builtin_amdgcn_mfma_f32_16x16x32_f16(hf, Wl[0][ks], Cl[0], 0, 0, 0);
                Cl[1] = __builtin_amdgcn_mfma_f32_16x16x32_f16(hf, Wl[1][ks], Cl[1], 0, 0, 0);
            }
#pragma unroll
            for (int nt = 0; nt < 2; ++nt)
#pragma unroll
                for (int r = 0; r < 4; ++r) {
                    float v = fmaf(Cl[nt][r], HL_INV, C[nt][r]) + b2v[nt];
                    acc[nt][r] += fmaxf(v, 0.0f);
                }
        }

        // write h (next chunk, i 4..7)
        if (c < 7) {
#pragma unroll
            for (int q = 0; q < 4; ++q) {
                half8 hf;
#pragma unroll
                for (int e = 0; e < 4; ++e) {
                    hf[e]     = (half_t)fmaxf(av[q][0][e] + Bw0[e], 0.0f);
                    hf[4 + e] = (half_t)fmaxf(av[q][1][e] + Bw1[e], 0.0f);
                }
                *(half8*)&hbuf[nxt][4 + q][w][lane8] = hf;
            }
        }
        __syncthreads();
    }

    // C layout: col = l15 (n), row = g4*4 + r (jj)
#pragma unroll
    for (int nt = 0; nt < 2; ++nt)
#pragma unroll
        for (int r = 0; r < 4; ++r)
            atomicAdd(&S[(size_t)(j0 + g4 * 4 + r) * F2D + w * 32 + nt * 16 + l15], acc[nt][r]);
}

// ---------------- k4: fused MFMA tail (round-5 verified) ----------------
#define AST 260   // LDS activation row stride (floats)

template<int NT, int NKS>
__device__ __forceinline__ void frag_gemm(const float* __restrict__ aPtr,
                                          const half_t* __restrict__ WhF,
                                          const half_t* __restrict__ WlF,
                                          const int* pB, int lane8,
                                          float4_t* Chi, float4_t* Clo) {
#pragma unroll
    for (int ks = 0; ks < NKS; ++ks) {
        float4_t a0 = *(const float4_t*)(aPtr + ks * 32);
        float4_t a1 = *(const float4_t*)(aPtr + ks * 32 + 4);
        half8 ah, al;
#pragma unroll
        for (int e = 0; e < 4; ++e) {
            half_t h0 = (half_t)a0[e];
            ah[e] = h0; al[e] = (half_t)((a0[e] - (float)h0) * 4096.0f);
            half_t h1 = (half_t)a1[e];
            ah[4+e] = h1; al[4+e] = (half_t)((a1[e] - (float)h1) * 4096.0f);
        }
#pragma unroll
        for (int nt = 0; nt < NT; ++nt) {
            half8 wh = *(const half8*)(WhF + pB[nt] + ks * 512 + lane8);
            half8 wl = *(const half8*)(WlF + pB[nt] + ks * 512 + lane8);
            Chi[nt] = __builtin_amdgcn_mfma_f32_16x16x32_f16(ah, wh, Chi[nt], 0, 0, 0);
            Clo[nt] = __builtin_amdgcn_mfma_f32_16x16x32_f16(ah, wl, Clo[nt], 0, 0, 0);
            Clo[nt] = __builtin_amdgcn_mfma_f32_16x16x32_f16(al, wh, Clo[nt], 0, 0, 0);
        }
    }
}

__global__ __launch_bounds__(512)
void k4_tail(const float* __restrict__ S,
             const float* __restrict__ x,
             const float* __restrict__ h0,
             const float* __restrict__ c0,
             const half_t* __restrict__ tail,
             const float* __restrict__ bf3,
             const float* __restrict__ bg1, const float* __restrict__ bg2,
             const float* __restrict__ bg3,
             const float* __restrict__ b_ih, const float* __restrict__ b_hh,
             const float* __restrict__ bo1, const float* __restrict__ bo2,
             float* __restrict__ out,
             float* __restrict__ hid_out,
             float* __restrict__ h_out,
             float* __restrict__ c_out) {
    __shared__ float bufA[16 * AST];
    __shared__ float bufB[16 * AST];
    __shared__ float bufC[16 * AST];
    const int tid = threadIdx.x;
    const int lane = tid & 63;
    const int w = tid >> 6;
    const int l15 = lane & 15;
    const int g4 = lane >> 4;
    const int r0 = blockIdx.x * 16;
    const int lane8 = lane * 8;

    for (int q = tid; q < 16 * 256; q += 512)
        bufC[(q >> 8) * AST + (q & 255)] = S[(size_t)(r0 + (q >> 8)) * 256 + (q & 255)];
    for (int q = tid; q < 16 * 128; q += 512)
        bufA[(q >> 7) * AST + (q & 127)] = x[(r0 + (q >> 7)) * 128 + (q & 127)];
    __syncthreads();

    const float* aFrag;
    int pB[4];
    float4_t Chi[4], Clo[4];

    // ---- SM ----
    {
        const int n = w * 16 + l15;
        pB[0] = w * 4096;
        Chi[0] = float4_t{0,0,0,0}; Clo[0] = float4_t{0,0,0,0};
        aFrag = bufC + l15 * AST + g4 * 8;
        frag_gemm<1, 8>(aFrag, tail + T3H, tail + T3H + 32768, pB, lane8, Chi, Clo);
        const float b = 512.0f * bf3[n];
#pragma unroll
        for (int r = 0; r < 4; ++r)
            bufA[(g4 * 4 + r) * AST + 128 + n] = Chi[0][r] + Clo[0][r] * HL_INV + b;
    }
    __syncthreads();

    // ---- g1 ----
    {
        pB[0] = (w * 2) * 4096; pB[1] = (w * 2 + 1) * 4096;
        Chi[0] = float4_t{0,0,0,0}; Clo[0] = float4_t{0,0,0,0};
        Chi[1] = float4_t{0,0,0,0}; Clo[1] = float4_t{0,0,0,0};
        aFrag = bufA + l15 * AST + g4 * 8;
        frag_gemm<2, 8>(aFrag, tail + G1H, tail + G1H + 65536, pB, lane8, Chi, Clo);
#pragma unroll
        for (int nt = 0; nt < 2; ++nt) {
            const int n = w * 32 + nt * 16 + l15;
            const float b = bg1[n];
#pragma unroll
            for (int r = 0; r < 4; ++r)
                bufB[(g4 * 4 + r) * AST + n] = fmaxf(Chi[nt][r] + Clo[nt][r] * HL_INV + b, 0.0f);
        }
    }
    __syncthreads();

    // ---- g2 (+ stage h0) ----
    {
        pB[0] = (w * 2) * 4096; pB[1] = (w * 2 + 1) * 4096;
        Chi[0] = float4_t{0,0,0,0}; Clo[0] = float4_t{0,0,0,0};
        Chi[1] = float4_t{0,0,0,0}; Clo[1] = float4_t{0,0,0,0};
        aFrag = bufB + l15 * AST + g4 * 8;
        frag_gemm<2, 8>(aFrag, tail + G2H, tail + G2H + 65536, pB, lane8, Chi, Clo);
#pragma unroll
        for (int nt = 0; nt < 2; ++nt) {
            const int n = w * 32 + nt * 16 + l15;
            const float b = bg2[n];
#pragma unroll
            for (int r = 0; r < 4; ++r)
                bufC[(g4 * 4 + r) * AST + n] = fmaxf(Chi[nt][r] + Clo[nt][r] * HL_INV + b, 0.0f);
        }
        for (int q = tid; q < 16 * 128; q += 512)
            bufA[(q >> 7) * AST + 128 + (q & 127)] = h0[(r0 + (q >> 7)) * 128 + (q & 127)];
    }
    __syncthreads();

    // ---- g3 ----
    {
        const int n = w * 16 + l15;
        pB[0] = w * 4096;
        Chi[0] = float4_t{0,0,0,0}; Clo[0] = float4_t{0,0,0,0};
        aFrag = bufC + l15 * AST + g4 * 8;
        frag_gemm<1, 8>(aFrag, tail + G3H, tail + G3H + 32768, pB, lane8, Chi, Clo);
        const float b = bg3[n];
#pragma unroll
        for (int r = 0; r < 4; ++r)
            bufA[(g4 * 4 + r) * AST + n] = Chi[0][r] + Clo[0][r] * HL_INV + b;
    }
    __syncthreads();

    // ---- gates + LSTM in-register ----
    {
#pragma unroll
        for (int nt = 0; nt < 4; ++nt) {
            pB[nt] = (w + nt * 8) * 4096;
            Chi[nt] = float4_t{0,0,0,0}; Clo[nt] = float4_t{0,0,0,0};
        }
        aFrag = bufA + l15 * AST + g4 * 8;
        frag_gemm<4, 8>(aFrag, tail + CATH, tail + CATH + 131072, pB, lane8, Chi, Clo);

        const int nh = w * 16 + l15;
        float bi = b_ih[nh]       + b_hh[nh];
        float bf = b_ih[128 + nh] + b_hh[128 + nh];
        float bg = b_ih[256 + nh] + b_hh[256 + nh];
        float bo = b_ih[384 + nh] + b_hh[384 + nh];
#pragma unroll
        for (int r = 0; r < 4; ++r) {
            const int row = r0 + g4 * 4 + r;
            float gi = sigmoidf_(Chi[0][r] + Clo[0][r] * HL_INV + bi);
            float gf = sigmoidf_(Chi[1][r] + Clo[1][r] * HL_INV + bf);
            float gg = tanhf(    Chi[2][r] + Clo[2][r] * HL_INV + bg);
            float go = sigmoidf_(Chi[3][r] + Clo[3][r] * HL_INV + bo);
            float c = gf * c0[row * 128 + nh] + gi * gg;
            float h = go * tanhf(c);
            bufC[(g4 * 4 + r) * AST + nh] = h;
            hid_out[row * 128 + nh] = h;
            h_out[row * 128 + nh]   = h;
            c_out[row * 128 + nh]   = c;
        }
    }
    __syncthreads();

    // ---- o1 ----
    {
        pB[0] = (w * 2) * 2048; pB[1] = (w * 2 + 1) * 2048;
        Chi[0] = float4_t{0,0,0,0}; Clo[0] = float4_t{0,0,0,0};
        Chi[1] = float4_t{0,0,0,0}; Clo[1] = float4_t{0,0,0,0};
        aFrag = bufC + l15 * AST + g4 * 8;
        frag_gemm<2, 4>(aFrag, tail + O1H, tail + O1H + 32768, pB, lane8, Chi, Clo);
#pragma unroll
        for (int nt = 0; nt < 2; ++nt) {
            const int n = w * 32 + nt * 16 + l15;
            const float b = bo1[n];
#pragma unroll
            for (int r = 0; r < 4; ++r)
                bufB[(g4 * 4 + r) * AST + n] = fmaxf(Chi[nt][r] + Clo[nt][r] * HL_INV + b, 0.0f);
        }
    }
    __syncthreads();

    // ---- o2 ----
    if (w < 4) {
        const int n = w * 16 + l15;
        pB[0] = w * 4096;
        Chi[0] = float4_t{0,0,0,0}; Clo[0] = float4_t{0,0,0,0};
        aFrag = bufB + l15 * AST + g4 * 8;
        frag_gemm<1, 8>(aFrag, tail + O2H, tail + O2H + 16384, pB, lane8, Chi, Clo);
        const float b = bo2[n];
#pragma unroll
        for (int r = 0; r < 4; ++r)
            out[(r0 + g4 * 4 + r) * OUTD + n] = Chi[0][r] + Clo[0][r] * HL_INV + b;
    }
}

// ---------------------------------------------------------------------------
extern "C" void kernel_launch(void* const* d_in, const int* in_sizes, int n_in,
                              void* d_out, int out_size, void* d_ws, size_t ws_size,
                              hipStream_t stream) {
    const float* x      = (const float*)d_in[0];
    const float* hidden = (const float*)d_in[1];
    const float* h0     = (const float*)d_in[2];
    const float* c0     = (const float*)d_in[3];
    const float* Wf1    = (const float*)d_in[4];
    const float* bf1    = (const float*)d_in[5];
    const float* Wf2    = (const float*)d_in[6];
    const float* bf2    = (const float*)d_in[7];
    const float* Wf3    = (const float*)d_in[8];
    const float* bf3    = (const float*)d_in[9];
    const float* Wg1    = (const float*)d_in[10];
    const float* bg1    = (const float*)d_in[11];
    const float* Wg2    = (const float*)d_in[12];
    const float* bg2    = (const float*)d_in[13];
    const float* Wg3    = (const float*)d_in[14];
    const float* bg3    = (const float*)d_in[15];
    const float* W_ih   = (const float*)d_in[16];
    const float* W_hh   = (const float*)d_in[17];
    const float* b_ih   = (const float*)d_in[18];
    const float* b_hh   = (const float*)d_in[19];
    const float* Wo1    = (const float*)d_in[20];
    const float* bo1    = (const float*)d_in[21];
    const float* Wo2    = (const float*)d_in[22];
    const float* bo2    = (const float*)d_in[23];

    char* wsb = (char*)d_ws;
    float*  A32  = (float*)(wsb + 0);
    float*  B32  = (float*)(wsb + 524288);
    half_t* W2H  = (half_t*)(wsb + 1048576);
    half_t* W2L  = (half_t*)(wsb + 1179648);
    float*  S    = (float*)(wsb + 1310720);
    half_t* tail = (half_t*)(wsb + WS_TAIL_B);
    float*  WT1  = (float*)(wsb + WS_WT1_B);

    float* outp  = (float*)d_out;              // [512,64]
    float* hid1  = (float*)d_out + 32768;      // hidden_new [512,128]
    float* hid2  = (float*)d_out + 98304;      // hidden_new[None]
    float* cout  = (float*)d_out + 163840;     // c_new[None]

    hipMemsetAsync(S, 0, (size_t)NN * F2D * sizeof(float), stream);

    k0_prep<<<dim3(132), dim3(256), 0, stream>>>(Wf1, Wf2, Wf3, Wg1, Wg2, Wg3,
                                                 W_ih, W_hh, Wo1, Wo2,
                                                 tail, W2H, W2L, WT1);

    k1_proj<<<dim3(128), dim3(256), 0, stream>>>(hidden, WT1, bf1, A32, B32);

    k2_pairwise<<<dim3(8, 32), dim3(512), 0, stream>>>(A32, B32, W2H, W2L, bf2, S);

    k4_tail<<<dim3(32), dim3(512), 0, stream>>>(S, x, h0, c0, tail,
                                                bf3, bg1, bg2, bg3,
                                                b_ih, b_hh, bo1, bo2,
                                                outp, hid1, hid2, cout);
}

// Round 10
// 205.313 us; speedup vs baseline: 2.0619x; 2.0222x over previous
//
#include <hip/hip_runtime.h>
#include <hip/hip_bf16.h>

// ---------------------------------------------------------------------------
// RRN forward, MI355X.
//   k0: unified prep — frag-pack ALL f16 hi/lo weights (Wf2 + 7 tail mats)
//       + Wf1 64x64 tile transpose -> WT1.
//   k1: A32/B32 projections (fp32) via WT1 (coalesced weight reads).
//   k2: pairwise MLP, 4-i micro-chunk double buffer (64KB LDS), ONE i of
//       prefetch in flight. 8-wave block => 2 waves/SIMD => 256 reg/wave
//       physical budget; W (128 regs) sits in AGPR half, arch stays < 128.
//       Round 8/9's 4-deep prefetch overflowed arch -> scratch spill (675MB).
//   k4: fused MFMA tail (round-5 verified).
// ---------------------------------------------------------------------------

#define NN   512
#define HH   128
#define F1D  256
#define F2D  256
#define OUTD 64
#define ICHUNK 64

typedef _Float16 half_t;
typedef _Float16 half8 __attribute__((ext_vector_type(8)));
typedef float float4_t __attribute__((ext_vector_type(4)));
typedef float float8_t __attribute__((ext_vector_type(8)));

__device__ __forceinline__ float sigmoidf_(float x) {
    return 1.0f / (1.0f + __expf(-x));
}

#define HL_INV 2.44140625e-4f

// ---- workspace layout (bytes) ----
// A32 0 (512K) | B32 524288 (512K) | W2H 1048576 (128K) | W2L 1179648 (128K)
// S 1310720 (512K) | tail 1835008..3342336 (1.507M) | WT1 3342336 (256K)
#define WS_TAIL_B 1835008
#define WS_WT1_B  3342336
// f16-element offsets within tail region (hi base; lo = hi + cnt):
#define T3H 0
#define G1H 65536
#define G2H 196608
#define G3H 327680
#define CATH 393216
#define O1H 655360
#define O2H 720896

// ---------------- k0: unified weight prep ----------------
__constant__ int p_cum[8]   = {16, 24, 40, 56, 64, 96, 112, 116};
__constant__ int p_K[8]     = {256, 256, 256, 256, 256, 256, 128, 256};
__constant__ int p_hioff[8] = {0, T3H, G1H, G2H, G3H, CATH, O1H, O2H};
__constant__ int p_cnt[8]   = {65536, 32768, 65536, 65536, 32768, 131072, 32768, 16384};

__global__ __launch_bounds__(256)
void k0_prep(const float* __restrict__ Wf1,
             const float* __restrict__ Wf2,
             const float* __restrict__ Wf3,
             const float* __restrict__ Wg1, const float* __restrict__ Wg2,
             const float* __restrict__ Wg3,
             const float* __restrict__ W_ih, const float* __restrict__ W_hh,
             const float* __restrict__ Wo1, const float* __restrict__ Wo2,
             half_t* __restrict__ tail,
             half_t* __restrict__ W2H, half_t* __restrict__ W2L,
             float* __restrict__ WT1) {
    __shared__ float slab[4096];
    __shared__ float tile[64][65];
    const int t = threadIdx.x;
    const int bid = blockIdx.x;

    if (bid < 116) {
        int m = 0;
        while (m < 7 && bid >= p_cum[m]) ++m;
        const int pl = bid - (m ? p_cum[m - 1] : 0);
        const int K = p_K[m];
        const int kshift = (K == 256) ? 8 : 7;
        const int n0 = pl * 16;

        const float* src;
        switch (m) {
            case 0: src = Wf2; break;
            case 1: src = Wf3; break;
            case 2: src = Wg1; break;
            case 3: src = Wg2; break;
            case 4: src = Wg3; break;
            case 6: src = Wo1; break;
            default: src = Wo2; break;  // m==7 ; m==5 handled below
        }
        for (int q = t; q < (16 * K) / 4; q += 256) {
            const int flat = q * 4;
            const int r = flat >> kshift;
            const int k = flat & (K - 1);
            float4_t v;
            if (m == 5) {
                v = (k < 128) ? *(const float4_t*)(W_ih + (n0 + r) * 128 + k)
                              : *(const float4_t*)(W_hh + (n0 + r) * 128 + (k - 128));
            } else {
                v = *(const float4_t*)(src + (size_t)(n0 + r) * K + k);
            }
            *(float4_t*)&slab[flat] = v;
        }
        __syncthreads();

        half_t *hi, *lo;
        if (m == 0) { hi = W2H; lo = W2L; }
        else        { hi = tail + p_hioff[m]; lo = hi + p_cnt[m]; }
        const int base = pl * (K << 4);
        for (int f0 = t * 8; f0 < 16 * K; f0 += 2048) {
            const int ks = f0 >> 9;
            const int g4 = (f0 >> 7) & 3;
            const int l15 = (f0 >> 3) & 15;
            const int k0 = ks * 32 + g4 * 8;
            float8_t v = *(const float8_t*)&slab[l15 * K + k0];
            half8 hv, lv;
#pragma unroll
            for (int e = 0; e < 8; ++e) {
                half_t h = (half_t)v[e];
                hv[e] = h;
                lv[e] = (half_t)((v[e] - (float)h) * 4096.0f);
            }
            *(half8*)(hi + base + f0) = hv;
            *(half8*)(lo + base + f0) = lv;
        }
    } else {
        // Wf1 [256][256] transpose -> WT1[k][n]
        const int local = bid - 116;
        const int tr = local >> 2, tc = local & 3;
#pragma unroll
        for (int q = 0; q < 16; ++q) {
            const int idx = q * 256 + t;
            const int ly = idx >> 6, lx = idx & 63;
            tile[ly][lx] = Wf1[(tr * 64 + ly) * 256 + tc * 64 + lx];
        }
        __syncthreads();
#pragma unroll
        for (int q = 0; q < 16; ++q) {
            const int idx = q * 256 + t;
            const int ly = idx >> 6, lx = idx & 63;
            WT1[(tc * 64 + ly) * 256 + tr * 64 + lx] = tile[lx][ly];
        }
    }
}

// ---------------- k1: projections (fp32 out), coalesced via WT1 ----------------
__global__ __launch_bounds__(256)
void k1_proj(const float* __restrict__ hidden,
             const float* __restrict__ WT1,
             const float* __restrict__ bf1,
             float* __restrict__ A32,
             float* __restrict__ B32) {
    __shared__ float hid[4][HH];
    const int t = threadIdx.x;
    const int i0 = blockIdx.x * 4;
    for (int q = t; q < 4 * HH; q += 256)
        hid[q >> 7][q & 127] = hidden[(i0 + (q >> 7)) * HH + (q & 127)];
    __syncthreads();

    float accA[4], accB[4];
    const float b = bf1[t];
#pragma unroll
    for (int r = 0; r < 4; ++r) { accA[r] = b; accB[r] = 0.0f; }

    const float* wcol = WT1 + t;
#pragma unroll 4
    for (int kk = 0; kk < HH; ++kk) {
        const float va = wcol[kk * 256];
        const float vb = wcol[(kk + 128) * 256];
#pragma unroll
        for (int r = 0; r < 4; ++r) {
            const float h = hid[r][kk];
            accA[r] = fmaf(h, va, accA[r]);
            accB[r] = fmaf(h, vb, accB[r]);
        }
    }
#pragma unroll
    for (int r = 0; r < 4; ++r) {
        A32[(i0 + r) * F1D + t] = accA[r];
        B32[(i0 + r) * F1D + t] = accB[r];
    }
}

// ---------------- k2: pairwise MLP, 4-i micro-chunk double buffer ----------------
// grid (8 i-macrochunks, 32 j-tiles) x 512 threads (8 waves), 1 block/CU.
// hbuf[2][4][8][512] = 64KB. Per 4-i chunk: ONE barrier; within the chunk,
// per i: {load a(i+4) -> 32 MFMA on buf[cur][q] -> produce h(i+4) to buf[nxt][q]}.
// Only ONE i of prefetch lives at a time (8 arch regs) - arch stays < 128.
__global__ __launch_bounds__(512, 2)
void k2_pairwise(const float* __restrict__ A32,
                 const float* __restrict__ B32,
                 const half_t* __restrict__ W2H,
                 const half_t* __restrict__ W2L,
                 const float* __restrict__ bf2,
                 float* __restrict__ S) {
    __shared__ half_t hbuf[2][4][8][512];   // 64 KB

    const int tid = threadIdx.x;
    const int lane = tid & 63;
    const int w = tid >> 6;           // wave 0..7
    const int l15 = lane & 15;
    const int g4 = lane >> 4;         // 0..3
    const int j0 = blockIdx.y * 16;
    const int i0 = blockIdx.x * ICHUNK;
    const int lane8 = lane * 8;

    // W fragments, frag-packed (coalesced): half8 idx = (w*2+nt)*512 + ks*64 + lane
    const half8* WH8 = (const half8*)W2H;
    const half8* WL8 = (const half8*)W2L;
    half8 Wh[2][8], Wl[2][8];
#pragma unroll
    for (int nt = 0; nt < 2; ++nt)
#pragma unroll
        for (int ks = 0; ks < 8; ++ks) {
            const int idx = (w * 2 + nt) * 512 + ks * 64 + lane;
            Wh[nt][ks] = WH8[idx];
            Wl[nt][ks] = WL8[idx];
        }
#pragma unroll
    for (int nt = 0; nt < 2; ++nt)
#pragma unroll
        for (int ks = 0; ks < 8; ++ks) {
            asm volatile("" : "+v"(Wh[nt][ks]));
            asm volatile("" : "+v"(Wl[nt][ks]));
        }

    // producer's B slice: B[j=l15][k = w*32 + g4*8 .. +8]
    float4_t Bw0 = *(const float4_t*)(B32 + (size_t)(j0 + l15) * F1D + w * 32 + g4 * 8);
    float4_t Bw1 = *(const float4_t*)(B32 + (size_t)(j0 + l15) * F1D + w * 32 + g4 * 8 + 4);

    float b2v[2];
#pragma unroll
    for (int nt = 0; nt < 2; ++nt) b2v[nt] = bf2[w * 32 + nt * 16 + l15];

    float4_t acc[2];
#pragma unroll
    for (int nt = 0; nt < 2; ++nt)
#pragma unroll
        for (int r = 0; r < 4; ++r) acc[nt][r] = 0.0f;

    // ---- prologue: produce i = 0..3 into buf 0 ----
#pragma unroll
    for (int q = 0; q < 4; ++q) {
        const float* Ap = A32 + (size_t)(i0 + q) * F1D + w * 32 + g4 * 8;
        float4_t a0 = *(const float4_t*)Ap;
        float4_t a1 = *(const float4_t*)(Ap + 4);
        half8 hf;
#pragma unroll
        for (int e = 0; e < 4; ++e) {
            hf[e]     = (half_t)fmaxf(a0[e] + Bw0[e], 0.0f);
            hf[4 + e] = (half_t)fmaxf(a1[e] + Bw1[e], 0.0f);
        }
        *(half8*)&hbuf[0][q][w][lane8] = hf;
    }
    __syncthreads();

    // ---- 16 chunks of 4 i ----
    for (int c = 0; c < 16; ++c) {
        const int cur = c & 1;
        const int nxt = cur ^ 1;
        const int ibase = i0 + (c + 1) * 4;

#pragma unroll
        for (int q = 0; q < 4; ++q) {
            // issue this q's next-chunk A load (latency hides under the MFMAs)
            float4_t a0, a1;
            if (c < 15) {
                const float* Ap = A32 + (size_t)(ibase + q) * F1D + w * 32 + g4 * 8;
                a0 = *(const float4_t*)Ap;
                a1 = *(const float4_t*)(Ap + 4);
            }

            float4_t C[2], Cl[2];
#pragma unroll
            for (int nt = 0; nt < 2; ++nt)
#pragma unroll
                for (int r = 0; r < 4; ++r) { C[nt][r] = 0.0f; Cl[nt][r] = 0.0f; }
#pragma unroll
            for (int ks = 0; ks < 8; ++ks) {
                half8 hf = *(const half8*)&hbuf[cur][q][ks][lane8];
                C[0]  = __builtin_amdgcn_mfma_f32_16x16x32_f16(hf, Wh[0][ks], C[0], 0, 0, 0);
                C[1]  = __builtin_amdgcn_mfma_f32_16x16x32_f16(hf, Wh[1][ks], C[1], 0, 0, 0);
                Cl[0] = __builtin_amdgcn_mfma_f32_16x16x32_f16(hf, Wl[0][ks], Cl[0], 0, 0, 0);
                Cl[1] = __builtin_amdgcn_mfma_f32_16x16x32_f16(hf, Wl[1][ks], Cl[1], 0, 0, 0);
            }

            // produce next-chunk h for this q
            if (c < 15) {
                half8 hf;
#pragma unroll
                for (int e = 0; e < 4; ++e) {
                    hf[e]     = (half_t)fmaxf(a0[e] + Bw0[e], 0.0f);
                    hf[4 + e] = (half_t)fmaxf(a1[e] + Bw1[e], 0.0f);
                }
                *(half8*)&hbuf[nxt][q][w][lane8] = hf;
            }

            // epilogue: h2 = relu(C + Cl/4096 + bf2), accumulate over i
#pragma unroll
            for (int nt = 0; nt < 2; ++nt)
#pragma unroll
                for (int r = 0; r < 4; ++r) {
                    float v = fmaf(Cl[nt][r], HL_INV, C[nt][r]) + b2v[nt];
                    acc[nt][r] += fmaxf(v, 0.0f);
                }
        }
        __syncthreads();
    }

    // C layout: col = l15 (n), row = g4*4 + r (jj)
#pragma unroll
    for (int nt = 0; nt < 2; ++nt)
#pragma unroll
        for (int r = 0; r < 4; ++r)
            atomicAdd(&S[(size_t)(j0 + g4 * 4 + r) * F2D + w * 32 + nt * 16 + l15], acc[nt][r]);
}

// ---------------- k4: fused MFMA tail (round-5 verified) ----------------
#define AST 260   // LDS activation row stride (floats)

template<int NT, int NKS>
__device__ __forceinline__ void frag_gemm(const float* __restrict__ aPtr,
                                          const half_t* __restrict__ WhF,
                                          const half_t* __restrict__ WlF,
                                          const int* pB, int lane8,
                                          float4_t* Chi, float4_t* Clo) {
#pragma unroll
    for (int ks = 0; ks < NKS; ++ks) {
        float4_t a0 = *(const float4_t*)(aPtr + ks * 32);
        float4_t a1 = *(const float4_t*)(aPtr + ks * 32 + 4);
        half8 ah, al;
#pragma unroll
        for (int e = 0; e < 4; ++e) {
            half_t h0 = (half_t)a0[e];
            ah[e] = h0; al[e] = (half_t)((a0[e] - (float)h0) * 4096.0f);
            half_t h1 = (half_t)a1[e];
            ah[4+e] = h1; al[4+e] = (half_t)((a1[e] - (float)h1) * 4096.0f);
        }
#pragma unroll
        for (int nt = 0; nt < NT; ++nt) {
            half8 wh = *(const half8*)(WhF + pB[nt] + ks * 512 + lane8);
            half8 wl = *(const half8*)(WlF + pB[nt] + ks * 512 + lane8);
            Chi[nt] = __builtin_amdgcn_mfma_f32_16x16x32_f16(ah, wh, Chi[nt], 0, 0, 0);
            Clo[nt] = __builtin_amdgcn_mfma_f32_16x16x32_f16(ah, wl, Clo[nt], 0, 0, 0);
            Clo[nt] = __builtin_amdgcn_mfma_f32_16x16x32_f16(al, wh, Clo[nt], 0, 0, 0);
        }
    }
}

__global__ __launch_bounds__(512)
void k4_tail(const float* __restrict__ S,
             const float* __restrict__ x,
             const float* __restrict__ h0,
             const float* __restrict__ c0,
             const half_t* __restrict__ tail,
             const float* __restrict__ bf3,
             const float* __restrict__ bg1, const float* __restrict__ bg2,
             const float* __restrict__ bg3,
             const float* __restrict__ b_ih, const float* __restrict__ b_hh,
             const float* __restrict__ bo1, const float* __restrict__ bo2,
             float* __restrict__ out,
             float* __restrict__ hid_out,
             float* __restrict__ h_out,
             float* __restrict__ c_out) {
    __shared__ float bufA[16 * AST];
    __shared__ float bufB[16 * AST];
    __shared__ float bufC[16 * AST];
    const int tid = threadIdx.x;
    const int lane = tid & 63;
    const int w = tid >> 6;
    const int l15 = lane & 15;
    const int g4 = lane >> 4;
    const int r0 = blockIdx.x * 16;
    const int lane8 = lane * 8;

    for (int q = tid; q < 16 * 256; q += 512)
        bufC[(q >> 8) * AST + (q & 255)] = S[(size_t)(r0 + (q >> 8)) * 256 + (q & 255)];
    for (int q = tid; q < 16 * 128; q += 512)
        bufA[(q >> 7) * AST + (q & 127)] = x[(r0 + (q >> 7)) * 128 + (q & 127)];
    __syncthreads();

    const float* aFrag;
    int pB[4];
    float4_t Chi[4], Clo[4];

    // ---- SM ----
    {
        const int n = w * 16 + l15;
        pB[0] = w * 4096;
        Chi[0] = float4_t{0,0,0,0}; Clo[0] = float4_t{0,0,0,0};
        aFrag = bufC + l15 * AST + g4 * 8;
        frag_gemm<1, 8>(aFrag, tail + T3H, tail + T3H + 32768, pB, lane8, Chi, Clo);
        const float b = 512.0f * bf3[n];
#pragma unroll
        for (int r = 0; r < 4; ++r)
            bufA[(g4 * 4 + r) * AST + 128 + n] = Chi[0][r] + Clo[0][r] * HL_INV + b;
    }
    __syncthreads();

    // ---- g1 ----
    {
        pB[0] = (w * 2) * 4096; pB[1] = (w * 2 + 1) * 4096;
        Chi[0] = float4_t{0,0,0,0}; Clo[0] = float4_t{0,0,0,0};
        Chi[1] = float4_t{0,0,0,0}; Clo[1] = float4_t{0,0,0,0};
        aFrag = bufA + l15 * AST + g4 * 8;
        frag_gemm<2, 8>(aFrag, tail + G1H, tail + G1H + 65536, pB, lane8, Chi, Clo);
#pragma unroll
        for (int nt = 0; nt < 2; ++nt) {
            const int n = w * 32 + nt * 16 + l15;
            const float b = bg1[n];
#pragma unroll
            for (int r = 0; r < 4; ++r)
                bufB[(g4 * 4 + r) * AST + n] = fmaxf(Chi[nt][r] + Clo[nt][r] * HL_INV + b, 0.0f);
        }
    }
    __syncthreads();

    // ---- g2 (+ stage h0) ----
    {
        pB[0] = (w * 2) * 4096; pB[1] = (w * 2 + 1) * 4096;
        Chi[0] = float4_t{0,0,0,0}; Clo[0] = float4_t{0,0,0,0};
        Chi[1] = float4_t{0,0,0,0}; Clo[1] = float4_t{0,0,0,0};
        aFrag = bufB + l15 * AST + g4 * 8;
        frag_gemm<2, 8>(aFrag, tail + G2H, tail + G2H + 65536, pB, lane8, Chi, Clo);
#pragma unroll
        for (int nt = 0; nt < 2; ++nt) {
            const int n = w * 32 + nt * 16 + l15;
            const float b = bg2[n];
#pragma unroll
            for (int r = 0; r < 4; ++r)
                bufC[(g4 * 4 + r) * AST + n] = fmaxf(Chi[nt][r] + Clo[nt][r] * HL_INV + b, 0.0f);
        }
        for (int q = tid; q < 16 * 128; q += 512)
            bufA[(q >> 7) * AST + 128 + (q & 127)] = h0[(r0 + (q >> 7)) * 128 + (q & 127)];
    }
    __syncthreads();

    // ---- g3 ----
    {
        const int n = w * 16 + l15;
        pB[0] = w * 4096;
        Chi[0] = float4_t{0,0,0,0}; Clo[0] = float4_t{0,0,0,0};
        aFrag = bufC + l15 * AST + g4 * 8;
        frag_gemm<1, 8>(aFrag, tail + G3H, tail + G3H + 32768, pB, lane8, Chi, Clo);
        const float b = bg3[n];
#pragma unroll
        for (int r = 0; r < 4; ++r)
            bufA[(g4 * 4 + r) * AST + n] = Chi[0][r] + Clo[0][r] * HL_INV + b;
    }
    __syncthreads();

    // ---- gates + LSTM in-register ----
    {
#pragma unroll
        for (int nt = 0; nt < 4; ++nt) {
            pB[nt] = (w + nt * 8) * 4096;
            Chi[nt] = float4_t{0,0,0,0}; Clo[nt] = float4_t{0,0,0,0};
        }
        aFrag = bufA + l15 * AST + g4 * 8;
        frag_gemm<4, 8>(aFrag, tail + CATH, tail + CATH + 131072, pB, lane8, Chi, Clo);

        const int nh = w * 16 + l15;
        float bi = b_ih[nh]       + b_hh[nh];
        float bf = b_ih[128 + nh] + b_hh[128 + nh];
        float bg = b_ih[256 + nh] + b_hh[256 + nh];
        float bo = b_ih[384 + nh] + b_hh[384 + nh];
#pragma unroll
        for (int r = 0; r < 4; ++r) {
            const int row = r0 + g4 * 4 + r;
            float gi = sigmoidf_(Chi[0][r] + Clo[0][r] * HL_INV + bi);
            float gf = sigmoidf_(Chi[1][r] + Clo[1][r] * HL_INV + bf);
            float gg = tanhf(    Chi[2][r] + Clo[2][r] * HL_INV + bg);
            float go = sigmoidf_(Chi[3][r] + Clo[3][r] * HL_INV + bo);
            float c = gf * c0[row * 128 + nh] + gi * gg;
            float h = go * tanhf(c);
            bufC[(g4 * 4 + r) * AST + nh] = h;
            hid_out[row * 128 + nh] = h;
            h_out[row * 128 + nh]   = h;
            c_out[row * 128 + nh]   = c;
        }
    }
    __syncthreads();

    // ---- o1 ----
    {
        pB[0] = (w * 2) * 2048; pB[1] = (w * 2 + 1) * 2048;
        Chi[0] = float4_t{0,0,0,0}; Clo[0] = float4_t{0,0,0,0};
        Chi[1] = float4_t{0,0,0,0}; Clo[1] = float4_t{0,0,0,0};
        aFrag = bufC + l15 * AST + g4 * 8;
        frag_gemm<2, 4>(aFrag, tail + O1H, tail + O1H + 32768, pB, lane8, Chi, Clo);
#pragma unroll
        for (int nt = 0; nt < 2; ++nt) {
            const int n = w * 32 + nt * 16 + l15;
            const float b = bo1[n];
#pragma unroll
            for (int r = 0; r < 4; ++r)
                bufB[(g4 * 4 + r) * AST + n] = fmaxf(Chi[nt][r] + Clo[nt][r] * HL_INV + b, 0.0f);
        }
    }
    __syncthreads();

    // ---- o2 ----
    if (w < 4) {
        const int n = w * 16 + l15;
        pB[0] = w * 4096;
        Chi[0] = float4_t{0,0,0,0}; Clo[0] = float4_t{0,0,0,0};
        aFrag = bufB + l15 * AST + g4 * 8;
        frag_gemm<1, 8>(aFrag, tail + O2H, tail + O2H + 16384, pB, lane8, Chi, Clo);
        const float b = bo2[n];
#pragma unroll
        for (int r = 0; r < 4; ++r)
            out[(r0 + g4 * 4 + r) * OUTD + n] = Chi[0][r] + Clo[0][r] * HL_INV + b;
    }
}

// ---------------------------------------------------------------------------
extern "C" void kernel_launch(void* const* d_in, const int* in_sizes, int n_in,
                              void* d_out, int out_size, void* d_ws, size_t ws_size,
                              hipStream_t stream) {
    const float* x      = (const float*)d_in[0];
    const float* hidden = (const float*)d_in[1];
    const float* h0     = (const float*)d_in[2];
    const float* c0     = (const float*)d_in[3];
    const float* Wf1    = (const float*)d_in[4];
    const float* bf1    = (const float*)d_in[5];
    const float* Wf2    = (const float*)d_in[6];
    const float* bf2    = (const float*)d_in[7];
    const float* Wf3    = (const float*)d_in[8];
    const float* bf3    = (const float*)d_in[9];
    const float* Wg1    = (const float*)d_in[10];
    const float* bg1    = (const float*)d_in[11];
    const float* Wg2    = (const float*)d_in[12];
    const float* bg2    = (const float*)d_in[13];
    const float* Wg3    = (const float*)d_in[14];
    const float* bg3    = (const float*)d_in[15];
    const float* W_ih   = (const float*)d_in[16];
    const float* W_hh   = (const float*)d_in[17];
    const float* b_ih   = (const float*)d_in[18];
    const float* b_hh   = (const float*)d_in[19];
    const float* Wo1    = (const float*)d_in[20];
    const float* bo1    = (const float*)d_in[21];
    const float* Wo2    = (const float*)d_in[22];
    const float* bo2    = (const float*)d_in[23];

    char* wsb = (char*)d_ws;
    float*  A32  = (float*)(wsb + 0);
    float*  B32  = (float*)(wsb + 524288);
    half_t* W2H  = (half_t*)(wsb + 1048576);
    half_t* W2L  = (half_t*)(wsb + 1179648);
    float*  S    = (float*)(wsb + 1310720);
    half_t* tail = (half_t*)(wsb + WS_TAIL_B);
    float*  WT1  = (float*)(wsb + WS_WT1_B);

    float* outp  = (float*)d_out;              // [512,64]
    float* hid1  = (float*)d_out + 32768;      // hidden_new [512,128]
    float* hid2  = (float*)d_out + 98304;      // hidden_new[None]
    float* cout  = (float*)d_out + 163840;     // c_new[None]

    hipMemsetAsync(S, 0, (size_t)NN * F2D * sizeof(float), stream);

    k0_prep<<<dim3(132), dim3(256), 0, stream>>>(Wf1, Wf2, Wf3, Wg1, Wg2, Wg3,
                                                 W_ih, W_hh, Wo1, Wo2,
                                                 tail, W2H, W2L, WT1);

    k1_proj<<<dim3(128), dim3(256), 0, stream>>>(hidden, WT1, bf1, A32, B32);

    k2_pairwise<<<dim3(8, 32), dim3(512), 0, stream>>>(A32, B32, W2H, W2L, bf2, S);

    k4_tail<<<dim3(32), dim3(512), 0, stream>>>(S, x, h0, c0, tail,
                                                bf3, bg1, bg2, bg3,
                                                b_ih, b_hh, bo1, bo2,
                                                outp, hid1, hid2, cout);
}

// Round 11
// 197.319 us; speedup vs baseline: 2.1454x; 1.0405x over previous
//
#include <hip/hip_runtime.h>
#include <hip/hip_bf16.h>

// ---------------------------------------------------------------------------
// RRN forward, MI355X.  3 dispatches: kP -> k2 -> k4.
//   kP: fused prep. Blocks 0-115: frag-pack all f16 hi/lo weights (Wf2 + 7
//       tail matrices). Blocks 116-243: A32/B32 projections (fp32, direct
//       Wf1 row-gather) + zero S (replaces memset + k0 + k1).
//   k2: pairwise MLP, 4-i micro-chunk double buffer (frozen from round 10:
//       65.5us, no spill, 2 waves/SIMD register-file plateau).
//   k4: fused MFMA tail (frozen from round 5).
// ---------------------------------------------------------------------------

#define NN   512
#define HH   128
#define F1D  256
#define F2D  256
#define OUTD 64
#define ICHUNK 64

typedef _Float16 half_t;
typedef _Float16 half8 __attribute__((ext_vector_type(8)));
typedef float float4_t __attribute__((ext_vector_type(4)));
typedef float float8_t __attribute__((ext_vector_type(8)));

__device__ __forceinline__ float sigmoidf_(float x) {
    return 1.0f / (1.0f + __expf(-x));
}

#define HL_INV 2.44140625e-4f

// ---- workspace layout (bytes) ----
// A32 0 (512K) | B32 524288 (512K) | W2H 1048576 (128K) | W2L 1179648 (128K)
// S 1310720 (512K) | tail 1835008..3342336 (1.507M)
#define WS_TAIL_B 1835008
// f16-element offsets within tail region (hi base; lo = hi + cnt):
#define T3H 0
#define G1H 65536
#define G2H 196608
#define G3H 327680
#define CATH 393216
#define O1H 655360
#define O2H 720896

// ---------------- kP: fused prep ----------------
// blocks 0..115: frag-pack one 16-row panel of one matrix (hi/lo f16).
// blocks 116..243: projection block pb = bid-116 (4 rows) + zero S slice.
__constant__ int p_cum[8]   = {16, 24, 40, 56, 64, 96, 112, 116};
__constant__ int p_K[8]     = {256, 256, 256, 256, 256, 256, 128, 256};
__constant__ int p_hioff[8] = {0, T3H, G1H, G2H, G3H, CATH, O1H, O2H};
__constant__ int p_cnt[8]   = {65536, 32768, 65536, 65536, 32768, 131072, 32768, 16384};

__global__ __launch_bounds__(256)
void kP_prep(const float* __restrict__ hidden,
             const float* __restrict__ Wf1,
             const float* __restrict__ bf1,
             const float* __restrict__ Wf2,
             const float* __restrict__ Wf3,
             const float* __restrict__ Wg1, const float* __restrict__ Wg2,
             const float* __restrict__ Wg3,
             const float* __restrict__ W_ih, const float* __restrict__ W_hh,
             const float* __restrict__ Wo1, const float* __restrict__ Wo2,
             half_t* __restrict__ tail,
             half_t* __restrict__ W2H, half_t* __restrict__ W2L,
             float* __restrict__ A32, float* __restrict__ B32,
             float* __restrict__ S) {
    __shared__ float slab[4096];
    const int t = threadIdx.x;
    const int bid = blockIdx.x;

    if (bid < 116) {
        // ---- weight frag-pack (identical to round-10 k0) ----
        int m = 0;
        while (m < 7 && bid >= p_cum[m]) ++m;
        const int pl = bid - (m ? p_cum[m - 1] : 0);
        const int K = p_K[m];
        const int kshift = (K == 256) ? 8 : 7;
        const int n0 = pl * 16;

        const float* src;
        switch (m) {
            case 0: src = Wf2; break;
            case 1: src = Wf3; break;
            case 2: src = Wg1; break;
            case 3: src = Wg2; break;
            case 4: src = Wg3; break;
            case 6: src = Wo1; break;
            default: src = Wo2; break;  // m==7 ; m==5 handled below
        }
        for (int q = t; q < (16 * K) / 4; q += 256) {
            const int flat = q * 4;
            const int r = flat >> kshift;
            const int k = flat & (K - 1);
            float4_t v;
            if (m == 5) {
                v = (k < 128) ? *(const float4_t*)(W_ih + (n0 + r) * 128 + k)
                              : *(const float4_t*)(W_hh + (n0 + r) * 128 + (k - 128));
            } else {
                v = *(const float4_t*)(src + (size_t)(n0 + r) * K + k);
            }
            *(float4_t*)&slab[flat] = v;
        }
        __syncthreads();

        half_t *hi, *lo;
        if (m == 0) { hi = W2H; lo = W2L; }
        else        { hi = tail + p_hioff[m]; lo = hi + p_cnt[m]; }
        const int base = pl * (K << 4);
        for (int f0 = t * 8; f0 < 16 * K; f0 += 2048) {
            const int ks = f0 >> 9;
            const int g4 = (f0 >> 7) & 3;
            const int l15 = (f0 >> 3) & 15;
            const int k0 = ks * 32 + g4 * 8;
            float8_t v = *(const float8_t*)&slab[l15 * K + k0];
            half8 hv, lv;
#pragma unroll
            for (int e = 0; e < 8; ++e) {
                half_t h = (half_t)v[e];
                hv[e] = h;
                lv[e] = (half_t)((v[e] - (float)h) * 4096.0f);
            }
            *(half8*)(hi + base + f0) = hv;
            *(half8*)(lo + base + f0) = lv;
        }
    } else {
        // ---- projection block (round-2-verified math) + S zeroing ----
        const int pb = bid - 116;          // 0..127
        const int i0 = pb * 4;

        // zero this block's 1024-float slice of S
        {
            float4_t z = {0.0f, 0.0f, 0.0f, 0.0f};
            *(float4_t*)(S + (size_t)pb * 1024 + t * 4) = z;
        }

        float* hid = slab;                 // [4][128] reuse
        for (int q = t; q < 4 * HH; q += 256)
            hid[q] = hidden[i0 * HH + q];
        __syncthreads();

        float accA[4], accB[4];
        const float b = bf1[t];
#pragma unroll
        for (int r = 0; r < 4; ++r) { accA[r] = b; accB[r] = 0.0f; }

        const float* wr = Wf1 + t * 256;
#pragma unroll 4
        for (int k = 0; k < HH; k += 4) {
            float4_t wa = *(const float4_t*)(wr + k);
            float4_t wb = *(const float4_t*)(wr + HH + k);
#pragma unroll
            for (int r = 0; r < 4; ++r) {
                const float* hp = &hid[r * HH + k];
                accA[r] += wa[0]*hp[0] + wa[1]*hp[1] + wa[2]*hp[2] + wa[3]*hp[3];
                accB[r] += wb[0]*hp[0] + wb[1]*hp[1] + wb[2]*hp[2] + wb[3]*hp[3];
            }
        }
#pragma unroll
        for (int r = 0; r < 4; ++r) {
            A32[(i0 + r) * F1D + t] = accA[r];
            B32[(i0 + r) * F1D + t] = accB[r];
        }
    }
}

// ---------------- k2: pairwise MLP (FROZEN, round 10) ----------------
// grid (8 i-macrochunks, 32 j-tiles) x 512 threads (8 waves), 1 block/CU.
// hbuf[2][4][8][512] = 64KB; W pinned (128 AGPR); 2 waves/SIMD plateau.
__global__ __launch_bounds__(512, 2)
void k2_pairwise(const float* __restrict__ A32,
                 const float* __restrict__ B32,
                 const half_t* __restrict__ W2H,
                 const half_t* __restrict__ W2L,
                 const float* __restrict__ bf2,
                 float* __restrict__ S) {
    __shared__ half_t hbuf[2][4][8][512];   // 64 KB

    const int tid = threadIdx.x;
    const int lane = tid & 63;
    const int w = tid >> 6;           // wave 0..7
    const int l15 = lane & 15;
    const int g4 = lane >> 4;         // 0..3
    const int j0 = blockIdx.y * 16;
    const int i0 = blockIdx.x * ICHUNK;
    const int lane8 = lane * 8;

    const half8* WH8 = (const half8*)W2H;
    const half8* WL8 = (const half8*)W2L;
    half8 Wh[2][8], Wl[2][8];
#pragma unroll
    for (int nt = 0; nt < 2; ++nt)
#pragma unroll
        for (int ks = 0; ks < 8; ++ks) {
            const int idx = (w * 2 + nt) * 512 + ks * 64 + lane;
            Wh[nt][ks] = WH8[idx];
            Wl[nt][ks] = WL8[idx];
        }
#pragma unroll
    for (int nt = 0; nt < 2; ++nt)
#pragma unroll
        for (int ks = 0; ks < 8; ++ks) {
            asm volatile("" : "+v"(Wh[nt][ks]));
            asm volatile("" : "+v"(Wl[nt][ks]));
        }

    float4_t Bw0 = *(const float4_t*)(B32 + (size_t)(j0 + l15) * F1D + w * 32 + g4 * 8);
    float4_t Bw1 = *(const float4_t*)(B32 + (size_t)(j0 + l15) * F1D + w * 32 + g4 * 8 + 4);

    float b2v[2];
#pragma unroll
    for (int nt = 0; nt < 2; ++nt) b2v[nt] = bf2[w * 32 + nt * 16 + l15];

    float4_t acc[2];
#pragma unroll
    for (int nt = 0; nt < 2; ++nt)
#pragma unroll
        for (int r = 0; r < 4; ++r) acc[nt][r] = 0.0f;

    // ---- prologue: produce i = 0..3 into buf 0 ----
#pragma unroll
    for (int q = 0; q < 4; ++q) {
        const float* Ap = A32 + (size_t)(i0 + q) * F1D + w * 32 + g4 * 8;
        float4_t a0 = *(const float4_t*)Ap;
        float4_t a1 = *(const float4_t*)(Ap + 4);
        half8 hf;
#pragma unroll
        for (int e = 0; e < 4; ++e) {
            hf[e]     = (half_t)fmaxf(a0[e] + Bw0[e], 0.0f);
            hf[4 + e] = (half_t)fmaxf(a1[e] + Bw1[e], 0.0f);
        }
        *(half8*)&hbuf[0][q][w][lane8] = hf;
    }
    __syncthreads();

    // ---- 16 chunks of 4 i ----
    for (int c = 0; c < 16; ++c) {
        const int cur = c & 1;
        const int nxt = cur ^ 1;
        const int ibase = i0 + (c + 1) * 4;

#pragma unroll
        for (int q = 0; q < 4; ++q) {
            float4_t a0, a1;
            if (c < 15) {
                const float* Ap = A32 + (size_t)(ibase + q) * F1D + w * 32 + g4 * 8;
                a0 = *(const float4_t*)Ap;
                a1 = *(const float4_t*)(Ap + 4);
            }

            float4_t C[2], Cl[2];
#pragma unroll
            for (int nt = 0; nt < 2; ++nt)
#pragma unroll
                for (int r = 0; r < 4; ++r) { C[nt][r] = 0.0f; Cl[nt][r] = 0.0f; }
#pragma unroll
            for (int ks = 0; ks < 8; ++ks) {
                half8 hf = *(const half8*)&hbuf[cur][q][ks][lane8];
                C[0]  = __builtin_amdgcn_mfma_f32_16x16x32_f16(hf, Wh[0][ks], C[0], 0, 0, 0);
                C[1]  = __builtin_amdgcn_mfma_f32_16x16x32_f16(hf, Wh[1][ks], C[1], 0, 0, 0);
                Cl[0] = __builtin_amdgcn_mfma_f32_16x16x32_f16(hf, Wl[0][ks], Cl[0], 0, 0, 0);
                Cl[1] = __builtin_amdgcn_mfma_f32_16x16x32_f16(hf, Wl[1][ks], Cl[1], 0, 0, 0);
            }

            if (c < 15) {
                half8 hf;
#pragma unroll
                for (int e = 0; e < 4; ++e) {
                    hf[e]     = (half_t)fmaxf(a0[e] + Bw0[e], 0.0f);
                    hf[4 + e] = (half_t)fmaxf(a1[e] + Bw1[e], 0.0f);
                }
                *(half8*)&hbuf[nxt][q][w][lane8] = hf;
            }

#pragma unroll
            for (int nt = 0; nt < 2; ++nt)
#pragma unroll
                for (int r = 0; r < 4; ++r) {
                    float v = fmaf(Cl[nt][r], HL_INV, C[nt][r]) + b2v[nt];
                    acc[nt][r] += fmaxf(v, 0.0f);
                }
        }
        __syncthreads();
    }

    // C layout: col = l15 (n), row = g4*4 + r (jj)
#pragma unroll
    for (int nt = 0; nt < 2; ++nt)
#pragma unroll
        for (int r = 0; r < 4; ++r)
            atomicAdd(&S[(size_t)(j0 + g4 * 4 + r) * F2D + w * 32 + nt * 16 + l15], acc[nt][r]);
}

// ---------------- k4: fused MFMA tail (FROZEN, round 5) ----------------
#define AST 260   // LDS activation row stride (floats)

template<int NT, int NKS>
__device__ __forceinline__ void frag_gemm(const float* __restrict__ aPtr,
                                          const half_t* __restrict__ WhF,
                                          const half_t* __restrict__ WlF,
                                          const int* pB, int lane8,
                                          float4_t* Chi, float4_t* Clo) {
#pragma unroll
    for (int ks = 0; ks < NKS; ++ks) {
        float4_t a0 = *(const float4_t*)(aPtr + ks * 32);
        float4_t a1 = *(const float4_t*)(aPtr + ks * 32 + 4);
        half8 ah, al;
#pragma unroll
        for (int e = 0; e < 4; ++e) {
            half_t h0 = (half_t)a0[e];
            ah[e] = h0; al[e] = (half_t)((a0[e] - (float)h0) * 4096.0f);
            half_t h1 = (half_t)a1[e];
            ah[4+e] = h1; al[4+e] = (half_t)((a1[e] - (float)h1) * 4096.0f);
        }
#pragma unroll
        for (int nt = 0; nt < NT; ++nt) {
            half8 wh = *(const half8*)(WhF + pB[nt] + ks * 512 + lane8);
            half8 wl = *(const half8*)(WlF + pB[nt] + ks * 512 + lane8);
            Chi[nt] = __builtin_amdgcn_mfma_f32_16x16x32_f16(ah, wh, Chi[nt], 0, 0, 0);
            Clo[nt] = __builtin_amdgcn_mfma_f32_16x16x32_f16(ah, wl, Clo[nt], 0, 0, 0);
            Clo[nt] = __builtin_amdgcn_mfma_f32_16x16x32_f16(al, wh, Clo[nt], 0, 0, 0);
        }
    }
}

__global__ __launch_bounds__(512)
void k4_tail(const float* __restrict__ S,
             const float* __restrict__ x,
             const float* __restrict__ h0,
             const float* __restrict__ c0,
             const half_t* __restrict__ tail,
             const float* __restrict__ bf3,
             const float* __restrict__ bg1, const float* __restrict__ bg2,
             const float* __restrict__ bg3,
             const float* __restrict__ b_ih, const float* __restrict__ b_hh,
             const float* __restrict__ bo1, const float* __restrict__ bo2,
             float* __restrict__ out,
             float* __restrict__ hid_out,
             float* __restrict__ h_out,
             float* __restrict__ c_out) {
    __shared__ float bufA[16 * AST];
    __shared__ float bufB[16 * AST];
    __shared__ float bufC[16 * AST];
    const int tid = threadIdx.x;
    const int lane = tid & 63;
    const int w = tid >> 6;
    const int l15 = lane & 15;
    const int g4 = lane >> 4;
    const int r0 = blockIdx.x * 16;
    const int lane8 = lane * 8;

    for (int q = tid; q < 16 * 256; q += 512)
        bufC[(q >> 8) * AST + (q & 255)] = S[(size_t)(r0 + (q >> 8)) * 256 + (q & 255)];
    for (int q = tid; q < 16 * 128; q += 512)
        bufA[(q >> 7) * AST + (q & 127)] = x[(r0 + (q >> 7)) * 128 + (q & 127)];
    __syncthreads();

    const float* aFrag;
    int pB[4];
    float4_t Chi[4], Clo[4];

    // ---- SM ----
    {
        const int n = w * 16 + l15;
        pB[0] = w * 4096;
        Chi[0] = float4_t{0,0,0,0}; Clo[0] = float4_t{0,0,0,0};
        aFrag = bufC + l15 * AST + g4 * 8;
        frag_gemm<1, 8>(aFrag, tail + T3H, tail + T3H + 32768, pB, lane8, Chi, Clo);
        const float b = 512.0f * bf3[n];
#pragma unroll
        for (int r = 0; r < 4; ++r)
            bufA[(g4 * 4 + r) * AST + 128 + n] = Chi[0][r] + Clo[0][r] * HL_INV + b;
    }
    __syncthreads();

    // ---- g1 ----
    {
        pB[0] = (w * 2) * 4096; pB[1] = (w * 2 + 1) * 4096;
        Chi[0] = float4_t{0,0,0,0}; Clo[0] = float4_t{0,0,0,0};
        Chi[1] = float4_t{0,0,0,0}; Clo[1] = float4_t{0,0,0,0};
        aFrag = bufA + l15 * AST + g4 * 8;
        frag_gemm<2, 8>(aFrag, tail + G1H, tail + G1H + 65536, pB, lane8, Chi, Clo);
#pragma unroll
        for (int nt = 0; nt < 2; ++nt) {
            const int n = w * 32 + nt * 16 + l15;
            const float b = bg1[n];
#pragma unroll
            for (int r = 0; r < 4; ++r)
                bufB[(g4 * 4 + r) * AST + n] = fmaxf(Chi[nt][r] + Clo[nt][r] * HL_INV + b, 0.0f);
        }
    }
    __syncthreads();

    // ---- g2 (+ stage h0) ----
    {
        pB[0] = (w * 2) * 4096; pB[1] = (w * 2 + 1) * 4096;
        Chi[0] = float4_t{0,0,0,0}; Clo[0] = float4_t{0,0,0,0};
        Chi[1] = float4_t{0,0,0,0}; Clo[1] = float4_t{0,0,0,0};
        aFrag = bufB + l15 * AST + g4 * 8;
        frag_gemm<2, 8>(aFrag, tail + G2H, tail + G2H + 65536, pB, lane8, Chi, Clo);
#pragma unroll
        for (int nt = 0; nt < 2; ++nt) {
            const int n = w * 32 + nt * 16 + l15;
            const float b = bg2[n];
#pragma unroll
            for (int r = 0; r < 4; ++r)
                bufC[(g4 * 4 + r) * AST + n] = fmaxf(Chi[nt][r] + Clo[nt][r] * HL_INV + b, 0.0f);
        }
        for (int q = tid; q < 16 * 128; q += 512)
            bufA[(q >> 7) * AST + 128 + (q & 127)] = h0[(r0 + (q >> 7)) * 128 + (q & 127)];
    }
    __syncthreads();

    // ---- g3 ----
    {
        const int n = w * 16 + l15;
        pB[0] = w * 4096;
        Chi[0] = float4_t{0,0,0,0}; Clo[0] = float4_t{0,0,0,0};
        aFrag = bufC + l15 * AST + g4 * 8;
        frag_gemm<1, 8>(aFrag, tail + G3H, tail + G3H + 32768, pB, lane8, Chi, Clo);
        const float b = bg3[n];
#pragma unroll
        for (int r = 0; r < 4; ++r)
            bufA[(g4 * 4 + r) * AST + n] = Chi[0][r] + Clo[0][r] * HL_INV + b;
    }
    __syncthreads();

    // ---- gates + LSTM in-register ----
    {
#pragma unroll
        for (int nt = 0; nt < 4; ++nt) {
            pB[nt] = (w + nt * 8) * 4096;
            Chi[nt] = float4_t{0,0,0,0}; Clo[nt] = float4_t{0,0,0,0};
        }
        aFrag = bufA + l15 * AST + g4 * 8;
        frag_gemm<4, 8>(aFrag, tail + CATH, tail + CATH + 131072, pB, lane8, Chi, Clo);

        const int nh = w * 16 + l15;
        float bi = b_ih[nh]       + b_hh[nh];
        float bf = b_ih[128 + nh] + b_hh[128 + nh];
        float bg = b_ih[256 + nh] + b_hh[256 + nh];
        float bo = b_ih[384 + nh] + b_hh[384 + nh];
#pragma unroll
        for (int r = 0; r < 4; ++r) {
            const int row = r0 + g4 * 4 + r;
            float gi = sigmoidf_(Chi[0][r] + Clo[0][r] * HL_INV + bi);
            float gf = sigmoidf_(Chi[1][r] + Clo[1][r] * HL_INV + bf);
            float gg = tanhf(    Chi[2][r] + Clo[2][r] * HL_INV + bg);
            float go = sigmoidf_(Chi[3][r] + Clo[3][r] * HL_INV + bo);
            float c = gf * c0[row * 128 + nh] + gi * gg;
            float h = go * tanhf(c);
            bufC[(g4 * 4 + r) * AST + nh] = h;
            hid_out[row * 128 + nh] = h;
            h_out[row * 128 + nh]   = h;
            c_out[row * 128 + nh]   = c;
        }
    }
    __syncthreads();

    // ---- o1 ----
    {
        pB[0] = (w * 2) * 2048; pB[1] = (w * 2 + 1) * 2048;
        Chi[0] = float4_t{0,0,0,0}; Clo[0] = float4_t{0,0,0,0};
        Chi[1] = float4_t{0,0,0,0}; Clo[1] = float4_t{0,0,0,0};
        aFrag = bufC + l15 * AST + g4 * 8;
        frag_gemm<2, 4>(aFrag, tail + O1H, tail + O1H + 32768, pB, lane8, Chi, Clo);
#pragma unroll
        for (int nt = 0; nt < 2; ++nt) {
            const int n = w * 32 + nt * 16 + l15;
            const float b = bo1[n];
#pragma unroll
            for (int r = 0; r < 4; ++r)
                bufB[(g4 * 4 + r) * AST + n] = fmaxf(Chi[nt][r] + Clo[nt][r] * HL_INV + b, 0.0f);
        }
    }
    __syncthreads();

    // ---- o2 ----
    if (w < 4) {
        const int n = w * 16 + l15;
        pB[0] = w * 4096;
        Chi[0] = float4_t{0,0,0,0}; Clo[0] = float4_t{0,0,0,0};
        aFrag = bufB + l15 * AST + g4 * 8;
        frag_gemm<1, 8>(aFrag, tail + O2H, tail + O2H + 16384, pB, lane8, Chi, Clo);
        const float b = bo2[n];
#pragma unroll
        for (int r = 0; r < 4; ++r)
            out[(r0 + g4 * 4 + r) * OUTD + n] = Chi[0][r] + Clo[0][r] * HL_INV + b;
    }
}

// ---------------------------------------------------------------------------
extern "C" void kernel_launch(void* const* d_in, const int* in_sizes, int n_in,
                              void* d_out, int out_size, void* d_ws, size_t ws_size,
                              hipStream_t stream) {
    const float* x      = (const float*)d_in[0];
    const float* hidden = (const float*)d_in[1];
    const float* h0     = (const float*)d_in[2];
    const float* c0     = (const float*)d_in[3];
    const float* Wf1    = (const float*)d_in[4];
    const float* bf1    = (const float*)d_in[5];
    const float* Wf2    = (const float*)d_in[6];
    const float* bf2    = (const float*)d_in[7];
    const float* Wf3    = (const float*)d_in[8];
    const float* bf3    = (const float*)d_in[9];
    const float* Wg1    = (const float*)d_in[10];
    const float* bg1    = (const float*)d_in[11];
    const float* Wg2    = (const float*)d_in[12];
    const float* bg2    = (const float*)d_in[13];
    const float* Wg3    = (const float*)d_in[14];
    const float* bg3    = (const float*)d_in[15];
    const float* W_ih   = (const float*)d_in[16];
    const float* W_hh   = (const float*)d_in[17];
    const float* b_ih   = (const float*)d_in[18];
    const float* b_hh   = (const float*)d_in[19];
    const float* Wo1    = (const float*)d_in[20];
    const float* bo1    = (const float*)d_in[21];
    const float* Wo2    = (const float*)d_in[22];
    const float* bo2    = (const float*)d_in[23];

    char* wsb = (char*)d_ws;
    float*  A32  = (float*)(wsb + 0);
    float*  B32  = (float*)(wsb + 524288);
    half_t* W2H  = (half_t*)(wsb + 1048576);
    half_t* W2L  = (half_t*)(wsb + 1179648);
    float*  S    = (float*)(wsb + 1310720);
    half_t* tail = (half_t*)(wsb + WS_TAIL_B);

    float* outp  = (float*)d_out;              // [512,64]
    float* hid1  = (float*)d_out + 32768;      // hidden_new [512,128]
    float* hid2  = (float*)d_out + 98304;      // hidden_new[None]
    float* cout  = (float*)d_out + 163840;     // c_new[None]

    kP_prep<<<dim3(244), dim3(256), 0, stream>>>(hidden, Wf1, bf1, Wf2,
                                                 Wf3, Wg1, Wg2, Wg3,
                                                 W_ih, W_hh, Wo1, Wo2,
                                                 tail, W2H, W2L,
                                                 A32, B32, S);

    k2_pairwise<<<dim3(8, 32), dim3(512), 0, stream>>>(A32, B32, W2H, W2L, bf2, S);

    k4_tail<<<dim3(32), dim3(512), 0, stream>>>(S, x, h0, c0, tail,
                                                bf3, bg1, bg2, bg3,
                                                b_ih, b_hh, bo1, bo2,
                                                outp, hid1, hid2, cout);
}